// Round 1
// baseline (1698.995 us; speedup 1.0000x reference)
//
#include <hip/hip_runtime.h>
#include <math.h>

// ---------------------------------------------------------------------------
// Problem constants (TransFusion3): B=2, C1=512, H1=W1=96, C2=256, H2=W2=192,
// D=256, NH=8, hd=32, WQ=24x24, WK=12x12. 64 windows per image (both streams),
// window i of q (24x24 @192) covers the same region as window i of k (12x12 @96).
// ---------------------------------------------------------------------------

#define HW1 9216L      // 96*96
#define HW2 36864L     // 192*192
#define M1  18432L     // 2*96*96
#define M2  73728L     // 2*192*192

// ---------------------------------------------------------------------------
// Generic tiled fp32 GEMM: C[m,n] = epi( sum_k A[k][m] * B[k][n] + bias[n] )
// AT=true : A is K-major (k stride = ldA), row m -> batch folding via hwA/batA
// AT=false: A is row-major (M,K), row stride ldA
// B is always row-major (K,N). EPI: 0 = none, 1 = exact GELU.
// BM=BN=64, BK=16, 256 threads, 4x4 microtile. All dims divide tiles exactly.
// ---------------------------------------------------------------------------
template<bool AT, int EPI>
__global__ __launch_bounds__(256) void gemm64(
    const float* __restrict__ A, const float* __restrict__ Bm,
    const float* __restrict__ bias, float* __restrict__ C,
    int N, int K, int ldA, int hwA, long batA)
{
    constexpr int BK = 16;
    __shared__ float As[BK][68];
    __shared__ float Bs[BK][68];
    const int tid = threadIdx.x;
    const int m0 = blockIdx.y * 64;
    const int n0 = blockIdx.x * 64;
    long aBase;
    if (AT) aBase = (long)(m0 / hwA) * batA + (long)(m0 % hwA);
    else    aBase = (long)m0 * ldA;
    const int tm = (tid >> 4) << 2;
    const int tn = (tid & 15) << 2;
    float acc[4][4] = {};
    for (int k0 = 0; k0 < K; k0 += BK) {
        if (AT) {
#pragma unroll
            for (int it = 0; it < 4; ++it) {
                int idx = tid + it * 256;
                int ky = idx >> 6, mx = idx & 63;
                As[ky][mx] = A[aBase + (long)(k0 + ky) * ldA + mx];
            }
        } else {
#pragma unroll
            for (int it = 0; it < 4; ++it) {
                int idx = tid + it * 256;
                int my = idx >> 4, kx = idx & 15;
                As[kx][my] = A[aBase + (long)my * ldA + (k0 + kx)];
            }
        }
#pragma unroll
        for (int it = 0; it < 4; ++it) {
            int idx = tid + it * 256;
            int ky = idx >> 6, nx = idx & 63;
            Bs[ky][nx] = Bm[(long)(k0 + ky) * N + (n0 + nx)];
        }
        __syncthreads();
#pragma unroll
        for (int kk = 0; kk < BK; ++kk) {
            float a[4], b[4];
#pragma unroll
            for (int i = 0; i < 4; ++i) a[i] = As[kk][tm + i];
#pragma unroll
            for (int j = 0; j < 4; ++j) b[j] = Bs[kk][tn + j];
#pragma unroll
            for (int i = 0; i < 4; ++i)
#pragma unroll
                for (int j = 0; j < 4; ++j) acc[i][j] += a[i] * b[j];
        }
        __syncthreads();
    }
#pragma unroll
    for (int i = 0; i < 4; ++i) {
        long row = (long)(m0 + tm + i) * N;
#pragma unroll
        for (int j = 0; j < 4; ++j) {
            float v = acc[i][j] + bias[n0 + tn + j];
            if (EPI == 1) v = 0.5f * v * (1.0f + erff(v * 0.70710678118654752f));
            C[row + n0 + tn + j] = v;
        }
    }
}

// ---------------------------------------------------------------------------
// Block-wide sum over 256 threads (4 waves of 64).
// ---------------------------------------------------------------------------
__device__ __forceinline__ float blocksum(float v, float* sb)
{
#pragma unroll
    for (int o = 32; o > 0; o >>= 1) v += __shfl_down(v, o, 64);
    int w = threadIdx.x >> 6;
    if ((threadIdx.x & 63) == 0) sb[w] = v;
    __syncthreads();
    float r = sb[0] + sb[1] + sb[2] + sb[3];
    __syncthreads();
    return r;
}

// LN over rows of 256; in-place safe. out = (x-m)/sqrt(v+1e-5)*g + b
__global__ __launch_bounds__(256) void ln_plain(
    const float* __restrict__ in, float* __restrict__ out,
    const float* __restrict__ g, const float* __restrict__ b)
{
    __shared__ float sb[4];
    long m = blockIdx.x;
    int t = threadIdx.x;
    float x = in[m * 256 + t];
    float mean = blocksum(x, sb) * (1.0f / 256.0f);
    float d = x - mean;
    float var = blocksum(d * d, sb) * (1.0f / 256.0f);
    out[m * 256 + t] = d * rsqrtf(var + 1e-5f) * g[t] + b[t];
}

// ---------------------------------------------------------------------------
// KtV: per (window, head) compute k_h^T @ v_h  (32x32 over 144 keys)
// windows enumerate (b, wy, wx) over the 8x8 grid of 12x12 x1-windows.
// ---------------------------------------------------------------------------
__global__ __launch_bounds__(256) void ktv_kernel(
    const float* __restrict__ kb, const float* __restrict__ vb,
    float* __restrict__ ktv)
{
    int blk = blockIdx.x;          // win*8 + head
    int win = blk >> 3, hd = blk & 7;
    int b = win >> 6, wy = (win >> 3) & 7, wx = win & 7;
    __shared__ float ks[144][33];
    __shared__ float vs[144][33];
    int t = threadIdx.x;
#pragma unroll
    for (int it = 0; it < 18; ++it) {
        int idx = t + it * 256;
        int p = idx >> 5, c = idx & 31;
        int py = p / 12, px = p % 12;
        long m = (long)b * HW1 + (long)(wy * 12 + py) * 96 + wx * 12 + px;
        ks[p][c] = kb[m * 256 + hd * 32 + c];
        vs[p][c] = vb[m * 256 + hd * 32 + c];
    }
    __syncthreads();
    int i = t >> 3, j0 = (t & 7) * 4;
    float acc[4] = {0.f, 0.f, 0.f, 0.f};
    for (int p = 0; p < 144; ++p) {
        float kv = ks[p][i];
#pragma unroll
        for (int jj = 0; jj < 4; ++jj) acc[jj] += kv * vs[p][j0 + jj];
    }
    long ob = ((long)blk * 32 + i) * 32 + j0;
#pragma unroll
    for (int jj = 0; jj < 4; ++jj) ktv[ob + jj] = acc[jj];
}

// ---------------------------------------------------------------------------
// qf = x2 (NHWC view) + q @ KtV   (per window/head, 576x32 @ 32x32)
// block = (window, py): 24 rows x 256 channels
// ---------------------------------------------------------------------------
__global__ __launch_bounds__(256) void qf_kernel(
    const float* __restrict__ qb, const float* __restrict__ ktv,
    const float* __restrict__ x2, float* __restrict__ qf)
{
    int blk = blockIdx.x;
    int win = blk / 24, py = blk % 24;
    int b = win >> 6, wy = (win >> 3) & 7, wx = win & 7;
    int d = threadIdx.x;
    int hd = d >> 5, j = d & 31;
    float kreg[32];
    const float* kt = ktv + ((long)(win * 8 + hd) * 32) * 32 + j;
#pragma unroll
    for (int i = 0; i < 32; ++i) kreg[i] = kt[i * 32];
    __shared__ float qs[24][257];
    int hh = wy * 24 + py;
    long mbase = (long)b * HW2 + (long)hh * 192 + wx * 24;
#pragma unroll
    for (int it = 0; it < 24; ++it) {
        int idx = d + it * 256;
        int r = idx >> 8, c = idx & 255;
        qs[r][c] = qb[(mbase + r) * 256 + c];
    }
    __syncthreads();
    const float* x2p = x2 + ((long)(b * 256 + d) * 192 + hh) * 192 + wx * 24;
    for (int r = 0; r < 24; ++r) {
        float o = 0.f;
#pragma unroll
        for (int i = 0; i < 32; ++i) o += qs[r][hd * 32 + i] * kreg[i];
        qf[(mbase + r) * 256 + d] = x2p[r] + o;
    }
}

// ---------------------------------------------------------------------------
// Sine pos with the reference's permuted-shape call: _sine_pos(8, 8, C)
// => npf = 4, dim_t = {1,1,100,100}; pos[gy][gx][c]:
//   gy<4 : enc((gx+1)*2pi/(8+1e-5))[gy]
//   gy>=4: enc((c +1)*2pi/(C+1e-5))[gy-4]
// enc(e) = {sin e, cos e, sin(e/100), cos(e/100)}
// ---------------------------------------------------------------------------
__device__ __forceinline__ float pe4(int t, float e)
{
    if (t == 0) return sinf(e);
    if (t == 1) return cosf(e);
    if (t == 2) return sinf(e * 0.01f);
    return cosf(e * 0.01f);
}

__global__ __launch_bounds__(256) void pool_q_k(
    const float* __restrict__ x2, float* __restrict__ qg)
{
    int blk = blockIdx.x;   // b*64 + gy*8 + gx
    int b = blk >> 6, gy = (blk >> 3) & 7, gx = blk & 7;
    int c = threadIdx.x;
    const float* p = x2 + ((long)(b * 256 + c) * 192 + gy * 24) * 192 + gx * 24;
    float s = 0.f;
    for (int i = 0; i < 24; ++i) {
        const float* pr = p + i * 192;
        for (int j = 0; j < 24; ++j) s += pr[j];
    }
    s *= (1.0f / 576.0f);
    const float TWO_PI = 6.283185307179586f;
    float pos;
    if (gy < 4) pos = pe4(gy,     (gx + 1) * (TWO_PI / (8.0f + 1e-5f)));
    else        pos = pe4(gy - 4, (c + 1)  * (TWO_PI / (256.0f + 1e-5f)));
    qg[(long)blk * 256 + c] = s + pos;
}

__global__ __launch_bounds__(256) void pool_k_k(
    const float* __restrict__ x1, float* __restrict__ kg)
{
    int blk = blockIdx.x;
    int b = blk >> 6, gy = (blk >> 3) & 7, gx = blk & 7;
    const float TWO_PI = 6.283185307179586f;
    for (int c = threadIdx.x; c < 512; c += 256) {
        const float* p = x1 + ((long)(b * 512 + c) * 96 + gy * 12) * 96 + gx * 12;
        float s = 0.f;
        for (int i = 0; i < 12; ++i) {
            const float* pr = p + i * 96;
            for (int j = 0; j < 12; ++j) s += pr[j];
        }
        s *= (1.0f / 144.0f);
        float pos;
        if (gy < 4) pos = pe4(gy,     (gx + 1) * (TWO_PI / (8.0f + 1e-5f)));
        else        pos = pe4(gy - 4, (c + 1)  * (TWO_PI / (512.0f + 1e-5f)));
        kg[(long)blk * 512 + c] = s + pos;
    }
}

// ---------------------------------------------------------------------------
// Global attention: per (b, head): S = q@k^T (64x64), softmax rows, og = S@v
// ---------------------------------------------------------------------------
__global__ __launch_bounds__(256) void gattn(
    const float* __restrict__ qg2, const float* __restrict__ kg2,
    const float* __restrict__ vg, float* __restrict__ og)
{
    __shared__ float qh[64][33], kh[64][33], vh[64][33];
    __shared__ float S[64][65];
    __shared__ float rinv[64];
    int blk = blockIdx.x;
    int b = blk >> 3, hd = blk & 7;
    int t = threadIdx.x;
#pragma unroll
    for (int it = 0; it < 8; ++it) {
        int idx = t + it * 256;
        int n = idx >> 5, i = idx & 31;
        long src = (long)(b * 64 + n) * 256 + hd * 32 + i;
        qh[n][i] = qg2[src];
        kh[n][i] = kg2[src];
        vh[n][i] = vg[src];
    }
    __syncthreads();
    int r = t >> 2, c0 = (t & 3) * 16;
    for (int c = c0; c < c0 + 16; ++c) {
        float s = 0.f;
#pragma unroll
        for (int i = 0; i < 32; ++i) s += qh[r][i] * kh[c][i];
        S[r][c] = s;
    }
    __syncthreads();
    if (t < 64) {
        float mx = -1e30f;
        for (int c = 0; c < 64; ++c) mx = fmaxf(mx, S[t][c]);
        float sm = 0.f;
        for (int c = 0; c < 64; ++c) {
            float e = expf(S[t][c] - mx);
            S[t][c] = e;
            sm += e;
        }
        rinv[t] = 1.0f / sm;
    }
    __syncthreads();
    int n = t >> 2, j0 = (t & 3) * 8;
    float inv = rinv[n];
    for (int j = j0; j < j0 + 8; ++j) {
        float s = 0.f;
        for (int c = 0; c < 64; ++c) s += S[n][c] * vh[c][j];
        og[(long)(b * 64 + n) * 256 + hd * 32 + j] = s * inv;
    }
}

// ---------------------------------------------------------------------------
// h = LN(qf + bilinear_ac(og, 8->192)) with n1_g/n1_b
// ---------------------------------------------------------------------------
__global__ __launch_bounds__(256) void ln_h_k(
    const float* __restrict__ qf, const float* __restrict__ og,
    float* __restrict__ out, const float* __restrict__ g,
    const float* __restrict__ bb)
{
    __shared__ float sb[4];
    int m = blockIdx.x;
    int t = threadIdx.x;
    int b = m / 36864, hw = m % 36864;
    int hh = hw / 192, ww = hw % 192;
    float fy = hh * (7.0f / 191.0f);
    int y0 = (int)fy; int y1 = min(y0 + 1, 7); float wy = fy - y0;
    float fx = ww * (7.0f / 191.0f);
    int x0 = (int)fx; int x1 = min(x0 + 1, 7); float wx = fx - x0;
    const float* base = og + (long)b * 64 * 256 + t;
    float c00 = base[(y0 * 8 + x0) * 256], c01 = base[(y0 * 8 + x1) * 256];
    float c10 = base[(y1 * 8 + x0) * 256], c11 = base[(y1 * 8 + x1) * 256];
    float ov = (1.f - wy) * ((1.f - wx) * c00 + wx * c01)
             + wy * ((1.f - wx) * c10 + wx * c11);
    float x = qf[(long)m * 256 + t] + ov;
    float mean = blocksum(x, sb) * (1.0f / 256.0f);
    float d = x - mean;
    float var = blocksum(d * d, sb) * (1.0f / 256.0f);
    out[(long)m * 256 + t] = d * rsqrtf(var + 1e-5f) * g[t] + bb[t];
}

// ---------------------------------------------------------------------------
// out = LN(mlp + bilinear_ac(sc, 96->192)) with n2_g/n2_b, write NCHW
// ---------------------------------------------------------------------------
__global__ __launch_bounds__(256) void final_k(
    const float* __restrict__ mlp, const float* __restrict__ sc,
    const float* __restrict__ g, const float* __restrict__ bb,
    float* __restrict__ out)
{
    __shared__ float sb[4];
    int m = blockIdx.x;
    int t = threadIdx.x;
    int b = m / 36864, hw = m % 36864;
    int hh = hw / 192, ww = hw % 192;
    float fy = hh * (95.0f / 191.0f);
    int y0 = (int)fy; int y1 = min(y0 + 1, 95); float wy = fy - y0;
    float fx = ww * (95.0f / 191.0f);
    int x0 = (int)fx; int x1 = min(x0 + 1, 95); float wx = fx - x0;
    const float* base = sc + (long)b * 96 * 96 * 256 + t;
    float c00 = base[(y0 * 96 + x0) * 256], c01 = base[(y0 * 96 + x1) * 256];
    float c10 = base[(y1 * 96 + x0) * 256], c11 = base[(y1 * 96 + x1) * 256];
    float sv = (1.f - wy) * ((1.f - wx) * c00 + wx * c01)
             + wy * ((1.f - wx) * c10 + wx * c11);
    float x = mlp[(long)m * 256 + t] + sv;
    float mean = blocksum(x, sb) * (1.0f / 256.0f);
    float d = x - mean;
    float var = blocksum(d * d, sb) * (1.0f / 256.0f);
    float r = d * rsqrtf(var + 1e-5f) * g[t] + bb[t];
    out[((long)(b * 256 + t) * 192 + hh) * 192 + ww] = r;
}

// ---------------------------------------------------------------------------
extern "C" void kernel_launch(void* const* d_in, const int* in_sizes, int n_in,
                              void* d_out, int out_size, void* d_ws, size_t ws_size,
                              hipStream_t stream)
{
    const float* x1     = (const float*)d_in[0];
    const float* x2     = (const float*)d_in[1];
    const float* q_w    = (const float*)d_in[2];
    const float* q_b    = (const float*)d_in[3];
    const float* k_w    = (const float*)d_in[4];
    const float* k_b    = (const float*)d_in[5];
    const float* v_w    = (const float*)d_in[6];
    const float* v_b    = (const float*)d_in[7];
    const float* q2_w   = (const float*)d_in[8];
    const float* q2_b   = (const float*)d_in[9];
    const float* k2_w   = (const float*)d_in[10];
    const float* k2_b   = (const float*)d_in[11];
    const float* v2_w   = (const float*)d_in[12];
    const float* v2_b   = (const float*)d_in[13];
    const float* proj_w = (const float*)d_in[14];
    const float* proj_b = (const float*)d_in[15];
    const float* proj_g = (const float*)d_in[16];
    const float* proj_bt= (const float*)d_in[17];
    const float* n1_g   = (const float*)d_in[18];
    const float* n1_b   = (const float*)d_in[19];
    const float* n2_g   = (const float*)d_in[20];
    const float* n2_b   = (const float*)d_in[21];
    const float* fc1_w  = (const float*)d_in[22];
    const float* fc1_b  = (const float*)d_in[23];
    const float* fc2_w  = (const float*)d_in[24];
    const float* fc2_b  = (const float*)d_in[25];
    float* out = (float*)d_out;

    // workspace layout (floats); total ~53.2M floats = ~213 MB
    float* ws  = (float*)d_ws;
    float* sc  = ws;                    // 18432*256 : LN'd proj of x1 (96x96)
    float* kb  = sc  + M1 * 256;        // 18432*256 : k proj   (dead after ktv)
    float* vb  = kb  + M1 * 256;        // 18432*256 : v proj   (dead after ktv)
    float* ktv = vb  + M1 * 256;        // 1024*1024 : per (win,head) 32x32
    float* qb  = ktv + 1048576L;        // 73728*256 : q proj -> later hln
    float* qfb = qb  + M2 * 256;        // 73728*256 : qf -> later mlp out
    float* qg  = qfb + M2 * 256;        // 128*256
    float* kg  = qg  + 32768L;          // 128*512
    float* qg2 = kg  + 65536L;          // 128*256
    float* kg2 = qg2 + 32768L;          // 128*256
    float* vgb = kg2 + 32768L;          // 128*256
    float* ogb = vgb + 32768L;          // 128*256
    float* h1c = kb;                    // fc1 chunk: 18432*512 (reuses kb+vb)

    dim3 blk(256);

    // 1) sc_raw = x1n @ proj_w + proj_b ; 2) LN in place
    gemm64<true, 0><<<dim3(4, 288), blk, 0, stream>>>(
        x1, proj_w, proj_b, sc, 256, 512, 9216, 9216, 512L * 9216);
    ln_plain<<<dim3(18432), blk, 0, stream>>>(sc, sc, proj_g, proj_bt);

    // 3-4) k, v projections of x1n
    gemm64<true, 0><<<dim3(4, 288), blk, 0, stream>>>(
        x1, k_w, k_b, kb, 256, 512, 9216, 9216, 512L * 9216);
    gemm64<true, 0><<<dim3(4, 288), blk, 0, stream>>>(
        x1, v_w, v_b, vb, 256, 512, 9216, 9216, 512L * 9216);

    // 5) per (window, head) K^T V
    ktv_kernel<<<dim3(1024), blk, 0, stream>>>(kb, vb, ktv);

    // 6) q projection of x2n
    gemm64<true, 0><<<dim3(4, 1152), blk, 0, stream>>>(
        x2, q_w, q_b, qb, 256, 256, 36864, 36864, 256L * 36864);

    // 7) qf = x2 + q @ KtV
    qf_kernel<<<dim3(3072), blk, 0, stream>>>(qb, ktv, x2, qfb);

    // 8) pooled q/k with (faithfully permuted) sine pos
    pool_q_k<<<dim3(128), blk, 0, stream>>>(x2, qg);
    pool_k_k<<<dim3(128), blk, 0, stream>>>(x1, kg);

    // 9-11) global projections
    gemm64<false, 0><<<dim3(4, 2), blk, 0, stream>>>(
        qg, q2_w, q2_b, qg2, 256, 256, 256, 1, 0);
    gemm64<false, 0><<<dim3(4, 2), blk, 0, stream>>>(
        kg, k2_w, k2_b, kg2, 256, 512, 512, 1, 0);
    gemm64<false, 0><<<dim3(4, 2), blk, 0, stream>>>(
        kg, v2_w, v2_b, vgb, 256, 512, 512, 1, 0);

    // 12) global softmax attention
    gattn<<<dim3(16), blk, 0, stream>>>(qg2, kg2, vgb, ogb);

    // 13) hln = LN(qf + upsample(og))   (hln reuses qb)
    ln_h_k<<<dim3(73728), blk, 0, stream>>>(qfb, ogb, qb, n1_g, n1_b);

    // 14-15) MLP, chunked x4 over rows; h1 chunk reuses kb+vb; out into qfb
    for (int c4 = 0; c4 < 4; ++c4) {
        const float* aoff = qb  + (long)c4 * 18432 * 256;
        float*       coff = qfb + (long)c4 * 18432 * 256;
        gemm64<false, 1><<<dim3(8, 288), blk, 0, stream>>>(
            aoff, fc1_w, fc1_b, h1c, 512, 256, 256, 1, 0);
        gemm64<false, 0><<<dim3(4, 288), blk, 0, stream>>>(
            h1c, fc2_w, fc2_b, coff, 256, 512, 512, 1, 0);
    }

    // 16) out = LN(mlp + upsample(sc)) -> NCHW
    final_k<<<dim3(73728), blk, 0, stream>>>(qfb, sc, n2_g, n2_b, out);
}

// Round 2
// 917.483 us; speedup vs baseline: 1.8518x; 1.8518x over previous
//
#include <hip/hip_runtime.h>
#include <math.h>

// ---------------------------------------------------------------------------
// Problem constants (TransFusion3): B=2, C1=512, H1=W1=96, C2=256, H2=W2=192,
// D=256, NH=8, hd=32, WQ=24x24, WK=12x12.
// ---------------------------------------------------------------------------

#define HW1 9216L      // 96*96
#define HW2 36864L     // 192*192
#define M1  18432L     // 2*96*96
#define M2  73728L     // 2*192*192

typedef __attribute__((ext_vector_type(8))) short short8;
typedef __attribute__((ext_vector_type(4))) float f32x4;

__device__ __forceinline__ short f2bf(float f)
{
    unsigned u = __builtin_bit_cast(unsigned, f);
    u = (u + 0x7fff + ((u >> 16) & 1)) >> 16;   // RNE
    return (short)u;
}

// ---------------------------------------------------------------------------
// MFMA bf16 GEMM: C[m,n] = epi( sum_k A(k,m)*B[k][n] + bias[n] )
//  AT=true : A is K-major (k stride ldA), batch-folded via hwA/batA (x1/x2 NCHW)
//  AT=false: A is row-major (M,K), row stride ldA
//  B row-major (K,N). EPI: 0 none, 1 exact GELU.
// Tile BM=128, BN=64, BK=32; 256 threads = 4 waves in 2x2, each wave 64x32
// (4x2 tiles of mfma_f32_16x16x32_bf16). fp32 accumulate.
// Fragment layouts (guide §3, m89/m120-verified):
//   A: m=lane&15, k=(lane>>4)*8+j   B: n=lane&15, k=(lane>>4)*8+j
//   D: col=lane&15, row=(lane>>4)*4+reg
// ---------------------------------------------------------------------------
template<bool AT, int EPI>
__global__ __launch_bounds__(256) void gemm_mfma(
    const float* __restrict__ A, const float* __restrict__ Bm,
    const float* __restrict__ bias, float* __restrict__ C,
    int N, int K, int ldA, int hwA, long batA)
{
    __shared__ short As[128][40];   // [m][k] pad->80B rows (16B aligned b128)
    __shared__ short Bs[64][40];    // [n][k]
    const int tid = threadIdx.x;
    const int m0 = blockIdx.y * 128;
    const int n0 = blockIdx.x * 64;
    long aBase;
    if (AT) aBase = (long)(m0 / hwA) * batA + (long)(m0 % hwA);
    else    aBase = 0;

    const int w    = tid >> 6;
    const int lane = tid & 63;
    const int wm   = (w & 1) * 64;
    const int wn   = (w >> 1) * 32;
    const int lm   = lane & 15;
    const int lq   = lane >> 4;

    f32x4 acc[4][2] = {};

    for (int k0 = 0; k0 < K; k0 += 32) {
        // ---- stage A ----
        if (AT) {
            int ml = tid & 127, kh = tid >> 7;           // kh in {0,1}: 16 k's
            const float* Ap = A + aBase + ml + (long)(k0 + kh * 16) * ldA;
            float v[16];
#pragma unroll
            for (int j = 0; j < 16; ++j) v[j] = Ap[(long)j * ldA];
            short8 s0, s1;
#pragma unroll
            for (int j = 0; j < 8; ++j) { s0[j] = f2bf(v[j]); s1[j] = f2bf(v[j + 8]); }
            *(short8*)&As[ml][kh * 16]     = s0;
            *(short8*)&As[ml][kh * 16 + 8] = s1;
        } else {
            int kq = tid & 3, mr = tid >> 2;             // 64 rows/pass, 2 passes
#pragma unroll
            for (int p = 0; p < 2; ++p) {
                int ml = mr + p * 64;
                const float* Ap = A + (long)(m0 + ml) * ldA + k0 + kq * 8;
                float4 a0 = *(const float4*)Ap;
                float4 a1 = *(const float4*)(Ap + 4);
                short8 s;
                s[0] = f2bf(a0.x); s[1] = f2bf(a0.y); s[2] = f2bf(a0.z); s[3] = f2bf(a0.w);
                s[4] = f2bf(a1.x); s[5] = f2bf(a1.y); s[6] = f2bf(a1.z); s[7] = f2bf(a1.w);
                *(short8*)&As[ml][kq * 8] = s;
            }
        }
        // ---- stage B (transpose K-major -> [n][k]) ----
        {
            int nl = tid & 63, kh = tid >> 6;            // kh in {0..3}: 8 k's
            const float* Bp = Bm + (long)(k0 + kh * 8) * N + n0 + nl;
            float v[8];
#pragma unroll
            for (int j = 0; j < 8; ++j) v[j] = Bp[(long)j * N];
            short8 s;
#pragma unroll
            for (int j = 0; j < 8; ++j) s[j] = f2bf(v[j]);
            *(short8*)&Bs[nl][kh * 8] = s;
        }
        __syncthreads();
        short8 af[4], bf[2];
#pragma unroll
        for (int r = 0; r < 4; ++r) af[r] = *(short8*)&As[wm + r * 16 + lm][lq * 8];
#pragma unroll
        for (int c = 0; c < 2; ++c) bf[c] = *(short8*)&Bs[wn + c * 16 + lm][lq * 8];
#pragma unroll
        for (int r = 0; r < 4; ++r)
#pragma unroll
            for (int c = 0; c < 2; ++c)
                acc[r][c] = __builtin_amdgcn_mfma_f32_16x16x32_bf16(
                    af[r], bf[c], acc[r][c], 0, 0, 0);
        __syncthreads();
    }

#pragma unroll
    for (int r = 0; r < 4; ++r) {
#pragma unroll
        for (int i = 0; i < 4; ++i) {
            int row = m0 + wm + r * 16 + lq * 4 + i;
            long rb = (long)row * N;
#pragma unroll
            for (int c = 0; c < 2; ++c) {
                int col = n0 + wn + c * 16 + lm;
                float v = acc[r][c][i] + bias[col];
                if (EPI == 1) v = 0.5f * v * (1.0f + erff(v * 0.70710678118654752f));
                C[rb + col] = v;
            }
        }
    }
}

// ---------------------------------------------------------------------------
// fp32 fallback tiled GEMM for the three tiny (M=128) global-branch GEMMs.
// ---------------------------------------------------------------------------
template<int EPI>
__global__ __launch_bounds__(256) void gemm64(
    const float* __restrict__ A, const float* __restrict__ Bm,
    const float* __restrict__ bias, float* __restrict__ C,
    int N, int K, int ldA)
{
    constexpr int BK = 16;
    __shared__ float As[BK][68];
    __shared__ float Bs[BK][68];
    const int tid = threadIdx.x;
    const int m0 = blockIdx.y * 64;
    const int n0 = blockIdx.x * 64;
    const int tm = (tid >> 4) << 2;
    const int tn = (tid & 15) << 2;
    float acc[4][4] = {};
    for (int k0 = 0; k0 < K; k0 += BK) {
#pragma unroll
        for (int it = 0; it < 4; ++it) {
            int idx = tid + it * 256;
            int my = idx >> 4, kx = idx & 15;
            As[kx][my] = A[(long)(m0 + my) * ldA + (k0 + kx)];
        }
#pragma unroll
        for (int it = 0; it < 4; ++it) {
            int idx = tid + it * 256;
            int ky = idx >> 6, nx = idx & 63;
            Bs[ky][nx] = Bm[(long)(k0 + ky) * N + (n0 + nx)];
        }
        __syncthreads();
#pragma unroll
        for (int kk = 0; kk < BK; ++kk) {
            float a[4], b[4];
#pragma unroll
            for (int i = 0; i < 4; ++i) a[i] = As[kk][tm + i];
#pragma unroll
            for (int j = 0; j < 4; ++j) b[j] = Bs[kk][tn + j];
#pragma unroll
            for (int i = 0; i < 4; ++i)
#pragma unroll
                for (int j = 0; j < 4; ++j) acc[i][j] += a[i] * b[j];
        }
        __syncthreads();
    }
#pragma unroll
    for (int i = 0; i < 4; ++i) {
        long row = (long)(m0 + tm + i) * N;
#pragma unroll
        for (int j = 0; j < 4; ++j) {
            float v = acc[i][j] + bias[n0 + tn + j];
            if (EPI == 1) v = 0.5f * v * (1.0f + erff(v * 0.70710678118654752f));
            C[row + n0 + tn + j] = v;
        }
    }
}

// ---------------------------------------------------------------------------
__device__ __forceinline__ float blocksum(float v, float* sb)
{
#pragma unroll
    for (int o = 32; o > 0; o >>= 1) v += __shfl_down(v, o, 64);
    int w = threadIdx.x >> 6;
    if ((threadIdx.x & 63) == 0) sb[w] = v;
    __syncthreads();
    float r = sb[0] + sb[1] + sb[2] + sb[3];
    __syncthreads();
    return r;
}

__global__ __launch_bounds__(256) void ln_plain(
    const float* __restrict__ in, float* __restrict__ out,
    const float* __restrict__ g, const float* __restrict__ b)
{
    __shared__ float sb[4];
    long m = blockIdx.x;
    int t = threadIdx.x;
    float x = in[m * 256 + t];
    float mean = blocksum(x, sb) * (1.0f / 256.0f);
    float d = x - mean;
    float var = blocksum(d * d, sb) * (1.0f / 256.0f);
    out[m * 256 + t] = d * rsqrtf(var + 1e-5f) * g[t] + b[t];
}

// ---------------------------------------------------------------------------
__global__ __launch_bounds__(256) void ktv_kernel(
    const float* __restrict__ kb, const float* __restrict__ vb,
    float* __restrict__ ktv)
{
    int blk = blockIdx.x;          // win*8 + head
    int win = blk >> 3, hd = blk & 7;
    int b = win >> 6, wy = (win >> 3) & 7, wx = win & 7;
    __shared__ float ks[144][33];
    __shared__ float vs[144][33];
    int t = threadIdx.x;
#pragma unroll
    for (int it = 0; it < 18; ++it) {
        int idx = t + it * 256;
        int p = idx >> 5, c = idx & 31;
        int py = p / 12, px = p % 12;
        long m = (long)b * HW1 + (long)(wy * 12 + py) * 96 + wx * 12 + px;
        ks[p][c] = kb[m * 256 + hd * 32 + c];
        vs[p][c] = vb[m * 256 + hd * 32 + c];
    }
    __syncthreads();
    int i = t >> 3, j0 = (t & 7) * 4;
    float acc[4] = {0.f, 0.f, 0.f, 0.f};
    for (int p = 0; p < 144; ++p) {
        float kv = ks[p][i];
#pragma unroll
        for (int jj = 0; jj < 4; ++jj) acc[jj] += kv * vs[p][j0 + jj];
    }
    long ob = ((long)blk * 32 + i) * 32 + j0;
#pragma unroll
    for (int jj = 0; jj < 4; ++jj) ktv[ob + jj] = acc[jj];
}

// ---------------------------------------------------------------------------
__global__ __launch_bounds__(256) void qf_kernel(
    const float* __restrict__ qb, const float* __restrict__ ktv,
    const float* __restrict__ x2, float* __restrict__ qf)
{
    int blk = blockIdx.x;
    int win = blk / 24, py = blk % 24;
    int b = win >> 6, wy = (win >> 3) & 7, wx = win & 7;
    int d = threadIdx.x;
    int hd = d >> 5, j = d & 31;
    float kreg[32];
    const float* kt = ktv + ((long)(win * 8 + hd) * 32) * 32 + j;
#pragma unroll
    for (int i = 0; i < 32; ++i) kreg[i] = kt[i * 32];
    __shared__ float qs[24][257];
    int hh = wy * 24 + py;
    long mbase = (long)b * HW2 + (long)hh * 192 + wx * 24;
#pragma unroll
    for (int it = 0; it < 24; ++it) {
        int idx = d + it * 256;
        int r = idx >> 8, c = idx & 255;
        qs[r][c] = qb[(mbase + r) * 256 + c];
    }
    __syncthreads();
    const float* x2p = x2 + ((long)(b * 256 + d) * 192 + hh) * 192 + wx * 24;
    for (int r = 0; r < 24; ++r) {
        float o = 0.f;
#pragma unroll
        for (int i = 0; i < 32; ++i) o += qs[r][hd * 32 + i] * kreg[i];
        qf[(mbase + r) * 256 + d] = x2p[r] + o;
    }
}

// ---------------------------------------------------------------------------
__device__ __forceinline__ float pe4(int t, float e)
{
    if (t == 0) return sinf(e);
    if (t == 1) return cosf(e);
    if (t == 2) return sinf(e * 0.01f);
    return cosf(e * 0.01f);
}

__global__ __launch_bounds__(256) void pool_q_k(
    const float* __restrict__ x2, float* __restrict__ qg)
{
    int blk = blockIdx.x;   // b*64 + gy*8 + gx
    int b = blk >> 6, gy = (blk >> 3) & 7, gx = blk & 7;
    int c = threadIdx.x;
    const float* p = x2 + ((long)(b * 256 + c) * 192 + gy * 24) * 192 + gx * 24;
    float s = 0.f;
    for (int i = 0; i < 24; ++i) {
        const float* pr = p + i * 192;
        for (int j = 0; j < 24; ++j) s += pr[j];
    }
    s *= (1.0f / 576.0f);
    const float TWO_PI = 6.283185307179586f;
    float pos;
    if (gy < 4) pos = pe4(gy,     (gx + 1) * (TWO_PI / (8.0f + 1e-5f)));
    else        pos = pe4(gy - 4, (c + 1)  * (TWO_PI / (256.0f + 1e-5f)));
    qg[(long)blk * 256 + c] = s + pos;
}

__global__ __launch_bounds__(256) void pool_k_k(
    const float* __restrict__ x1, float* __restrict__ kg)
{
    int blk = blockIdx.x;
    int b = blk >> 6, gy = (blk >> 3) & 7, gx = blk & 7;
    const float TWO_PI = 6.283185307179586f;
    for (int c = threadIdx.x; c < 512; c += 256) {
        const float* p = x1 + ((long)(b * 512 + c) * 96 + gy * 12) * 96 + gx * 12;
        float s = 0.f;
        for (int i = 0; i < 12; ++i) {
            const float* pr = p + i * 96;
            for (int j = 0; j < 12; ++j) s += pr[j];
        }
        s *= (1.0f / 144.0f);
        float pos;
        if (gy < 4) pos = pe4(gy,     (gx + 1) * (TWO_PI / (8.0f + 1e-5f)));
        else        pos = pe4(gy - 4, (c + 1)  * (TWO_PI / (512.0f + 1e-5f)));
        kg[(long)blk * 512 + c] = s + pos;
    }
}

// ---------------------------------------------------------------------------
__global__ __launch_bounds__(256) void gattn(
    const float* __restrict__ qg2, const float* __restrict__ kg2,
    const float* __restrict__ vg, float* __restrict__ og)
{
    __shared__ float qh[64][33], kh[64][33], vh[64][33];
    __shared__ float S[64][65];
    __shared__ float rinv[64];
    int blk = blockIdx.x;
    int b = blk >> 3, hd = blk & 7;
    int t = threadIdx.x;
#pragma unroll
    for (int it = 0; it < 8; ++it) {
        int idx = t + it * 256;
        int n = idx >> 5, i = idx & 31;
        long src = (long)(b * 64 + n) * 256 + hd * 32 + i;
        qh[n][i] = qg2[src];
        kh[n][i] = kg2[src];
        vh[n][i] = vg[src];
    }
    __syncthreads();
    int r = t >> 2, c0 = (t & 3) * 16;
    for (int c = c0; c < c0 + 16; ++c) {
        float s = 0.f;
#pragma unroll
        for (int i = 0; i < 32; ++i) s += qh[r][i] * kh[c][i];
        S[r][c] = s;
    }
    __syncthreads();
    if (t < 64) {
        float mx = -1e30f;
        for (int c = 0; c < 64; ++c) mx = fmaxf(mx, S[t][c]);
        float sm = 0.f;
        for (int c = 0; c < 64; ++c) {
            float e = expf(S[t][c] - mx);
            S[t][c] = e;
            sm += e;
        }
        rinv[t] = 1.0f / sm;
    }
    __syncthreads();
    int n = t >> 2, j0 = (t & 3) * 8;
    float inv = rinv[n];
    for (int j = j0; j < j0 + 8; ++j) {
        float s = 0.f;
        for (int c = 0; c < 64; ++c) s += S[n][c] * vh[c][j];
        og[(long)(b * 64 + n) * 256 + hd * 32 + j] = s * inv;
    }
}

// ---------------------------------------------------------------------------
__global__ __launch_bounds__(256) void ln_h_k(
    const float* __restrict__ qf, const float* __restrict__ og,
    float* __restrict__ out, const float* __restrict__ g,
    const float* __restrict__ bb)
{
    __shared__ float sb[4];
    int m = blockIdx.x;
    int t = threadIdx.x;
    int b = m / 36864, hw = m % 36864;
    int hh = hw / 192, ww = hw % 192;
    float fy = hh * (7.0f / 191.0f);
    int y0 = (int)fy; int y1 = min(y0 + 1, 7); float wy = fy - y0;
    float fx = ww * (7.0f / 191.0f);
    int x0 = (int)fx; int x1 = min(x0 + 1, 7); float wx = fx - x0;
    const float* base = og + (long)b * 64 * 256 + t;
    float c00 = base[(y0 * 8 + x0) * 256], c01 = base[(y0 * 8 + x1) * 256];
    float c10 = base[(y1 * 8 + x0) * 256], c11 = base[(y1 * 8 + x1) * 256];
    float ov = (1.f - wy) * ((1.f - wx) * c00 + wx * c01)
             + wy * ((1.f - wx) * c10 + wx * c11);
    float x = qf[(long)m * 256 + t] + ov;
    float mean = blocksum(x, sb) * (1.0f / 256.0f);
    float d = x - mean;
    float var = blocksum(d * d, sb) * (1.0f / 256.0f);
    out[(long)m * 256 + t] = d * rsqrtf(var + 1e-5f) * g[t] + bb[t];
}

// ---------------------------------------------------------------------------
// out = LN(mlp + bilinear_ac(sc, 96->192)) with n2_g/n2_b -> NCHW.
// 32-ww strip per block; LDS transpose so NCHW writes are lane-contiguous.
// ---------------------------------------------------------------------------
__global__ __launch_bounds__(256) void final_k2(
    const float* __restrict__ mlp, const float* __restrict__ sc,
    const float* __restrict__ g, const float* __restrict__ bb,
    float* __restrict__ out)
{
    __shared__ float lnb[32][258];
    int blk = blockIdx.x;              // b*1152 + hh*6 + strip
    int b = blk / 1152;
    int rem = blk - b * 1152;
    int hh = rem / 6, ww0 = (rem - (rem / 6) * 6) * 32;
    int wv = threadIdx.x >> 6, lane = threadIdx.x & 63;
    int c0 = lane * 4;
    float4 g4 = *(const float4*)(g + c0);
    float4 b4 = *(const float4*)(bb + c0);
    float fy = hh * (95.0f / 191.0f);
    int y0 = (int)fy; int y1 = min(y0 + 1, 95); float wy = fy - y0;
    const float* scb = sc + (long)b * 9216 * 256 + c0;
#pragma unroll
    for (int i = 0; i < 8; ++i) {
        int p = wv * 8 + i;
        int ww = ww0 + p;
        float fx = ww * (95.0f / 191.0f);
        int x0 = (int)fx; int x1 = min(x0 + 1, 95); float wx = fx - x0;
        float4 c00 = *(const float4*)(scb + (long)(y0 * 96 + x0) * 256);
        float4 c01 = *(const float4*)(scb + (long)(y0 * 96 + x1) * 256);
        float4 c10 = *(const float4*)(scb + (long)(y1 * 96 + x0) * 256);
        float4 c11 = *(const float4*)(scb + (long)(y1 * 96 + x1) * 256);
        long m = ((long)b * 192 + hh) * 192 + ww;
        float4 xv = *(const float4*)(mlp + m * 256 + c0);
        float w00 = (1.f - wy) * (1.f - wx), w01 = (1.f - wy) * wx;
        float w10 = wy * (1.f - wx),         w11 = wy * wx;
        xv.x += w00 * c00.x + w01 * c01.x + w10 * c10.x + w11 * c11.x;
        xv.y += w00 * c00.y + w01 * c01.y + w10 * c10.y + w11 * c11.y;
        xv.z += w00 * c00.z + w01 * c01.z + w10 * c10.z + w11 * c11.z;
        xv.w += w00 * c00.w + w01 * c01.w + w10 * c10.w + w11 * c11.w;
        float s  = xv.x + xv.y + xv.z + xv.w;
        float s2 = xv.x * xv.x + xv.y * xv.y + xv.z * xv.z + xv.w * xv.w;
#pragma unroll
        for (int o = 32; o > 0; o >>= 1) {
            s  += __shfl_xor(s,  o, 64);
            s2 += __shfl_xor(s2, o, 64);
        }
        float mean = s * (1.0f / 256.0f);
        float var  = s2 * (1.0f / 256.0f) - mean * mean;
        float rs   = rsqrtf(var + 1e-5f);
        lnb[p][c0 + 0] = (xv.x - mean) * rs * g4.x + b4.x;
        lnb[p][c0 + 1] = (xv.y - mean) * rs * g4.y + b4.y;
        lnb[p][c0 + 2] = (xv.z - mean) * rs * g4.z + b4.z;
        lnb[p][c0 + 3] = (xv.w - mean) * rs * g4.w + b4.w;
    }
    __syncthreads();
    int tw = threadIdx.x & 31, cg = threadIdx.x >> 5;
#pragma unroll
    for (int cc = 0; cc < 32; ++cc) {
        int c = cg * 32 + cc;
        out[((long)(b * 256 + c) * 192 + hh) * 192 + ww0 + tw] = lnb[tw][c];
    }
}

// ---------------------------------------------------------------------------
extern "C" void kernel_launch(void* const* d_in, const int* in_sizes, int n_in,
                              void* d_out, int out_size, void* d_ws, size_t ws_size,
                              hipStream_t stream)
{
    const float* x1     = (const float*)d_in[0];
    const float* x2     = (const float*)d_in[1];
    const float* q_w    = (const float*)d_in[2];
    const float* q_b    = (const float*)d_in[3];
    const float* k_w    = (const float*)d_in[4];
    const float* k_b    = (const float*)d_in[5];
    const float* v_w    = (const float*)d_in[6];
    const float* v_b    = (const float*)d_in[7];
    const float* q2_w   = (const float*)d_in[8];
    const float* q2_b   = (const float*)d_in[9];
    const float* k2_w   = (const float*)d_in[10];
    const float* k2_b   = (const float*)d_in[11];
    const float* v2_w   = (const float*)d_in[12];
    const float* v2_b   = (const float*)d_in[13];
    const float* proj_w = (const float*)d_in[14];
    const float* proj_b = (const float*)d_in[15];
    const float* proj_g = (const float*)d_in[16];
    const float* proj_bt= (const float*)d_in[17];
    const float* n1_g   = (const float*)d_in[18];
    const float* n1_b   = (const float*)d_in[19];
    const float* n2_g   = (const float*)d_in[20];
    const float* n2_b   = (const float*)d_in[21];
    const float* fc1_w  = (const float*)d_in[22];
    const float* fc1_b  = (const float*)d_in[23];
    const float* fc2_w  = (const float*)d_in[24];
    const float* fc2_b  = (const float*)d_in[25];
    float* out = (float*)d_out;

    // workspace layout (floats); ~53.2M floats = ~213 MB
    float* ws  = (float*)d_ws;
    float* sc  = ws;                    // 18432*256
    float* kb  = sc  + M1 * 256;        // 18432*256 (dead after ktv)
    float* vb  = kb  + M1 * 256;        // 18432*256 (dead after ktv)
    float* ktv = vb  + M1 * 256;        // 1024*1024
    float* qb  = ktv + 1048576L;        // 73728*256
    float* qfb = qb  + M2 * 256;        // 73728*256
    float* qg  = qfb + M2 * 256;        // 128*256
    float* kg  = qg  + 32768L;          // 128*512
    float* qg2 = kg  + 65536L;          // 128*256
    float* kg2 = qg2 + 32768L;          // 128*256
    float* vgb = kg2 + 32768L;          // 128*256
    float* ogb = vgb + 32768L;          // 128*256
    float* h1c = kb;                    // fc1 chunk 18432*512 (reuses kb+vb)

    dim3 blk(256);

    // 1) sc = LN(x1n @ proj_w + proj_b)
    gemm_mfma<true, 0><<<dim3(4, 144), blk, 0, stream>>>(
        x1, proj_w, proj_b, sc, 256, 512, 9216, 9216, 512L * 9216);
    ln_plain<<<dim3(18432), blk, 0, stream>>>(sc, sc, proj_g, proj_bt);

    // 2-3) k, v projections of x1n
    gemm_mfma<true, 0><<<dim3(4, 144), blk, 0, stream>>>(
        x1, k_w, k_b, kb, 256, 512, 9216, 9216, 512L * 9216);
    gemm_mfma<true, 0><<<dim3(4, 144), blk, 0, stream>>>(
        x1, v_w, v_b, vb, 256, 512, 9216, 9216, 512L * 9216);

    // 4) per (window, head) K^T V
    ktv_kernel<<<dim3(1024), blk, 0, stream>>>(kb, vb, ktv);

    // 5) q projection of x2n
    gemm_mfma<true, 0><<<dim3(4, 576), blk, 0, stream>>>(
        x2, q_w, q_b, qb, 256, 256, 36864, 36864, 256L * 36864);

    // 6) qf = x2 + q @ KtV
    qf_kernel<<<dim3(3072), blk, 0, stream>>>(qb, ktv, x2, qfb);

    // 7) pooled q/k with (faithfully permuted) sine pos
    pool_q_k<<<dim3(128), blk, 0, stream>>>(x2, qg);
    pool_k_k<<<dim3(128), blk, 0, stream>>>(x1, kg);

    // 8-10) global projections (tiny, fp32)
    gemm64<0><<<dim3(4, 2), blk, 0, stream>>>(qg, q2_w, q2_b, qg2, 256, 256, 256);
    gemm64<0><<<dim3(4, 2), blk, 0, stream>>>(kg, k2_w, k2_b, kg2, 256, 512, 512);
    gemm64<0><<<dim3(4, 2), blk, 0, stream>>>(kg, v2_w, v2_b, vgb, 256, 512, 512);

    // 11) global softmax attention
    gattn<<<dim3(16), blk, 0, stream>>>(qg2, kg2, vgb, ogb);

    // 12) hln = LN(qf + upsample(og))  (into qb)
    ln_h_k<<<dim3(73728), blk, 0, stream>>>(qfb, ogb, qb, n1_g, n1_b);

    // 13-14) MLP, chunked x4 over rows (h1 chunk reuses kb+vb)
    for (int c4 = 0; c4 < 4; ++c4) {
        const float* aoff = qb  + (long)c4 * 18432 * 256;
        float*       coff = qfb + (long)c4 * 18432 * 256;
        gemm_mfma<false, 1><<<dim3(8, 144), blk, 0, stream>>>(
            aoff, fc1_w, fc1_b, h1c, 512, 256, 256, 1, 0);
        gemm_mfma<false, 0><<<dim3(4, 144), blk, 0, stream>>>(
            h1c, fc2_w, fc2_b, coff, 256, 512, 512, 1, 0);
    }

    // 15) out = LN(mlp + upsample(sc)) -> NCHW
    final_k2<<<dim3(2304), blk, 0, stream>>>(qfb, sc, n2_g, n2_b, out);
}

// Round 3
// 780.153 us; speedup vs baseline: 2.1778x; 1.1760x over previous
//
#include <hip/hip_runtime.h>
#include <math.h>

// ---------------------------------------------------------------------------
// TransFusion3: B=2, C1=512, H1=W1=96, C2=256, H2=W2=192, D=256, NH=8, hd=32,
// WQ=24x24, WK=12x12. 64 windows per image; q-window i aligns with k-window i.
// ---------------------------------------------------------------------------

#define HW1 9216L      // 96*96
#define HW2 36864L     // 192*192
#define M1  18432L     // 2*96*96
#define M2  73728L     // 2*192*192

typedef __attribute__((ext_vector_type(8))) short short8;
typedef __attribute__((ext_vector_type(4))) float f32x4;
typedef unsigned short u16;

__device__ __forceinline__ short f2bf(float f)
{
    unsigned u = __builtin_bit_cast(unsigned, f);
    u = (u + 0x7fff + ((u >> 16) & 1)) >> 16;   // RNE
    return (short)u;
}
__device__ __forceinline__ float bf2f(u16 u)
{
    unsigned x = ((unsigned)u) << 16;
    return __builtin_bit_cast(float, x);
}
__device__ __forceinline__ float gelu_exact(float v)
{
    return 0.5f * v * (1.0f + erff(v * 0.70710678118654752f));
}

// ---------------------------------------------------------------------------
// gemm_at: C[m][n] = sum_k A(k,m)*B[k][n] + bias[n], A fp32 K-major (NCHW x1),
// outputs 256-wide each; split-N: blocks with n0>=256 use the second B/bias/C.
// BM=128, BN=64, BK=32; mfma_f32_16x16x32_bf16; TC=float (direct store) or
// u16 (bf16 store via LDS repack).
// ---------------------------------------------------------------------------
template<typename TC>
__global__ __launch_bounds__(256) void gemm_at(
    const float* __restrict__ A,
    const float* __restrict__ B1, const float* __restrict__ b1, TC* __restrict__ C1,
    const float* __restrict__ B2, const float* __restrict__ b2, TC* __restrict__ C2,
    int K, int ldA, int hwA, long batA)
{
    __shared__ short pool[9216];           // As[128][40] | Bs[64][40]; ob[128][72]
    short* As = pool;
    short* Bs = pool + 128 * 40;
    const int tid = threadIdx.x;
    const int m0 = blockIdx.y * 128;
    int n0 = blockIdx.x * 64;
    const float* Bm; const float* bias; TC* C;
    if (n0 < 256) { Bm = B1; bias = b1; C = C1; }
    else          { Bm = B2; bias = b2; C = C2; n0 -= 256; }
    const long aBase = (long)(m0 / hwA) * batA + (long)(m0 % hwA);

    const int w = tid >> 6, lane = tid & 63;
    const int wm = (w & 1) * 64, wn = (w >> 1) * 32;
    const int lm = lane & 15, lq = lane >> 4;

    f32x4 acc[4][2] = {};

    for (int k0 = 0; k0 < K; k0 += 32) {
        {   // stage A: 128 m x 32 k
            int ml = tid & 127, kh = tid >> 7;         // kh: 16 k's each
            const float* Ap = A + aBase + ml + (long)(k0 + kh * 16) * ldA;
            float v[16];
#pragma unroll
            for (int j = 0; j < 16; ++j) v[j] = Ap[(long)j * ldA];
            short8 s0, s1;
#pragma unroll
            for (int j = 0; j < 8; ++j) { s0[j] = f2bf(v[j]); s1[j] = f2bf(v[j + 8]); }
            *(short8*)&As[ml * 40 + kh * 16]     = s0;
            *(short8*)&As[ml * 40 + kh * 16 + 8] = s1;
        }
        {   // stage B: 64 n x 32 k (weights row-major [K][256])
            int nl = tid & 63, kh = tid >> 6;
            const float* Bp = Bm + (long)(k0 + kh * 8) * 256 + n0 + nl;
            short8 s;
#pragma unroll
            for (int j = 0; j < 8; ++j) s[j] = f2bf(Bp[(long)j * 256]);
            *(short8*)&Bs[nl * 40 + kh * 8] = s;
        }
        __syncthreads();
        short8 af[4], bfr[2];
#pragma unroll
        for (int r = 0; r < 4; ++r) af[r] = *(short8*)&As[(wm + r * 16 + lm) * 40 + lq * 8];
#pragma unroll
        for (int c = 0; c < 2; ++c) bfr[c] = *(short8*)&Bs[(wn + c * 16 + lm) * 40 + lq * 8];
#pragma unroll
        for (int r = 0; r < 4; ++r)
#pragma unroll
            for (int c = 0; c < 2; ++c)
                acc[r][c] = __builtin_amdgcn_mfma_f32_16x16x32_bf16(af[r], bfr[c], acc[r][c], 0, 0, 0);
        __syncthreads();
    }

    if constexpr (sizeof(TC) == 4) {
#pragma unroll
        for (int r = 0; r < 4; ++r)
#pragma unroll
            for (int i = 0; i < 4; ++i) {
                long row = (long)(m0 + wm + r * 16 + lq * 4 + i) * 256;
#pragma unroll
                for (int c = 0; c < 2; ++c) {
                    int col = n0 + wn + c * 16 + lm;
                    ((float*)C)[row + col] = acc[r][c][i] + bias[col];
                }
            }
    } else {
        short* ob = pool;   // [128][72] bf16 (aliases As/Bs; barrier already passed)
#pragma unroll
        for (int r = 0; r < 4; ++r)
#pragma unroll
            for (int i = 0; i < 4; ++i) {
                int row = wm + r * 16 + lq * 4 + i;
#pragma unroll
                for (int c = 0; c < 2; ++c) {
                    int col = n0 + wn + c * 16 + lm;
                    ob[row * 72 + wn + c * 16 + lm] = f2bf(acc[r][c][i] + bias[col]);
                }
            }
        __syncthreads();
        int m = tid >> 1, half = (tid & 1) * 32;
        u16* Cp = (u16*)C + (long)(m0 + m) * 256 + n0 + half;
#pragma unroll
        for (int q = 0; q < 4; ++q)
            *(short8*)(Cp + q * 8) = *(short8*)&ob[m * 72 + half + q * 8];
    }
}

// ---------------------------------------------------------------------------
// gemm_bf16rm: A bf16 row-major [M][ldA], B fp32 [K][N]. BM=128,BN=64,BK=64.
// EPI: 0 none, 1 exact gelu. TC float (direct) or u16 (bf16 via repack).
// ---------------------------------------------------------------------------
template<int EPI, typename TC>
__global__ __launch_bounds__(256) void gemm_bf16rm(
    const u16* __restrict__ A, const float* __restrict__ Bm,
    const float* __restrict__ bias, TC* __restrict__ C,
    int N, int K, int ldA)
{
    __shared__ short pool[128 * 72 + 64 * 72];
    short* As = pool;              // [128][72]
    short* Bs = pool + 128 * 72;   // [64][72]
    const int tid = threadIdx.x;
    const int m0 = blockIdx.y * 128;
    const int n0 = blockIdx.x * 64;
    const int w = tid >> 6, lane = tid & 63;
    const int wm = (w & 1) * 64, wn = (w >> 1) * 32;
    const int lm = lane & 15, lq = lane >> 4;

    f32x4 acc[4][2] = {};

    for (int k0 = 0; k0 < K; k0 += 64) {
        {   // stage A: 128 rows x 64 k, straight bf16 copy (2 threads/row)
            int m = tid >> 1, kh = (tid & 1) * 32;
            const u16* Ap = A + (long)(m0 + m) * ldA + k0 + kh;
#pragma unroll
            for (int q = 0; q < 4; ++q)
                *(short8*)&As[m * 72 + kh + q * 8] = *(const short8*)(Ap + q * 8);
        }
        {   // stage B: 64 n x 64 k
            int nl = tid & 63, kb0 = (tid >> 6) * 16;
            const float* Bp = Bm + (long)(k0 + kb0) * N + n0 + nl;
            short8 s0, s1;
#pragma unroll
            for (int j = 0; j < 8; ++j) {
                s0[j] = f2bf(Bp[(long)j * N]);
                s1[j] = f2bf(Bp[(long)(j + 8) * N]);
            }
            *(short8*)&Bs[nl * 72 + kb0]     = s0;
            *(short8*)&Bs[nl * 72 + kb0 + 8] = s1;
        }
        __syncthreads();
#pragma unroll
        for (int kk = 0; kk < 64; kk += 32) {
            short8 af[4], bfr[2];
#pragma unroll
            for (int r = 0; r < 4; ++r) af[r] = *(short8*)&As[(wm + r * 16 + lm) * 72 + kk + lq * 8];
#pragma unroll
            for (int c = 0; c < 2; ++c) bfr[c] = *(short8*)&Bs[(wn + c * 16 + lm) * 72 + kk + lq * 8];
#pragma unroll
            for (int r = 0; r < 4; ++r)
#pragma unroll
                for (int c = 0; c < 2; ++c)
                    acc[r][c] = __builtin_amdgcn_mfma_f32_16x16x32_bf16(af[r], bfr[c], acc[r][c], 0, 0, 0);
        }
        __syncthreads();
    }

    if constexpr (sizeof(TC) == 4) {
#pragma unroll
        for (int r = 0; r < 4; ++r)
#pragma unroll
            for (int i = 0; i < 4; ++i) {
                long row = (long)(m0 + wm + r * 16 + lq * 4 + i) * N;
#pragma unroll
                for (int c = 0; c < 2; ++c) {
                    int col = n0 + wn + c * 16 + lm;
                    float v = acc[r][c][i] + bias[col];
                    if (EPI == 1) v = gelu_exact(v);
                    ((float*)C)[row + col] = v;
                }
            }
    } else {
        short* ob = pool;   // [128][72]
#pragma unroll
        for (int r = 0; r < 4; ++r)
#pragma unroll
            for (int i = 0; i < 4; ++i) {
                int row = wm + r * 16 + lq * 4 + i;
#pragma unroll
                for (int c = 0; c < 2; ++c) {
                    int col = n0 + wn + c * 16 + lm;
                    float v = acc[r][c][i] + bias[col];
                    if (EPI == 1) v = gelu_exact(v);
                    ob[row * 72 + wn + c * 16 + lm] = f2bf(v);
                }
            }
        __syncthreads();
        int m = tid >> 1, half = (tid & 1) * 32;
        u16* Cp = (u16*)C + (long)(m0 + m) * N + n0 + half;
#pragma unroll
        for (int q = 0; q < 4; ++q)
            *(short8*)(Cp + q * 8) = *(short8*)&ob[m * 72 + half + q * 8];
    }
}

// ---------------------------------------------------------------------------
// Fused q-projection + window attention: qf = x2 + (x2n@q_w + q_b) @ KtV.
// Block = one window's 4 hh-rows (96 pixels) x 64 channels (2 heads), so the
// per-thread KtV column loads once into registers. grid (4, 768).
// ---------------------------------------------------------------------------
__global__ __launch_bounds__(256) void qproj_qf(
    const float* __restrict__ x2, const float* __restrict__ qw,
    const float* __restrict__ qbias, const float* __restrict__ ktv,
    float* __restrict__ qf)
{
    __shared__ float pool[2 * 96 * 68];     // 52224 B
    short* As = (short*)pool;               // [96][40]
    short* Bs = (short*)pool + 96 * 40;     // [64][40]
    float* qs = pool;                       // [96][68]  (phase 2, aliases As/Bs)
    float* xr = pool + 96 * 68;             // [96][68]

    const int t = threadIdx.x;
    const int n0 = blockIdx.x * 64;
    const int gy = blockIdx.y;              // 0..767
    const int rb = gy % 6, win = gy / 6;
    const int b = win >> 6, wy = (win >> 3) & 7, wx = win & 7;
    const int hh0 = wy * 24 + rb * 4;
    const long chan0 = (long)b * 256 * HW2;
    const long pix0  = (long)hh0 * 192 + wx * 24;

    const int w = t >> 6, lane = t & 63;
    const int wm = (w & 1) * 48, wn = (w >> 1) * 32;
    const int lm = lane & 15, lq = lane >> 4;

    f32x4 acc[3][2] = {};

    for (int k0 = 0; k0 < 256; k0 += 32) {
        {   // stage A: 96 px x 32 k from x2 NCHW (k = channel)
            int k = t >> 3, pc = (t & 7) * 12;
            int r = pc / 24, c0 = pc % 24;
            const float* Ap = x2 + chan0 + (long)(k0 + k) * HW2 + pix0 + r * 192 + c0;
            float4 a0 = *(const float4*)Ap;
            float4 a1 = *(const float4*)(Ap + 4);
            float4 a2 = *(const float4*)(Ap + 8);
            float v[12] = {a0.x,a0.y,a0.z,a0.w, a1.x,a1.y,a1.z,a1.w, a2.x,a2.y,a2.z,a2.w};
#pragma unroll
            for (int j = 0; j < 12; ++j) As[(pc + j) * 40 + k] = f2bf(v[j]);
        }
        {   // stage B: 64 n x 32 k
            int nl = t & 63, kh = t >> 6;
            const float* Bp = qw + (long)(k0 + kh * 8) * 256 + n0 + nl;
            short8 s;
#pragma unroll
            for (int j = 0; j < 8; ++j) s[j] = f2bf(Bp[(long)j * 256]);
            *(short8*)&Bs[nl * 40 + kh * 8] = s;
        }
        __syncthreads();
        short8 af[3], bfr[2];
#pragma unroll
        for (int r = 0; r < 3; ++r) af[r] = *(short8*)&As[(wm + r * 16 + lm) * 40 + lq * 8];
#pragma unroll
        for (int c = 0; c < 2; ++c) bfr[c] = *(short8*)&Bs[(wn + c * 16 + lm) * 40 + lq * 8];
#pragma unroll
        for (int r = 0; r < 3; ++r)
#pragma unroll
            for (int c = 0; c < 2; ++c)
                acc[r][c] = __builtin_amdgcn_mfma_f32_16x16x32_bf16(af[r], bfr[c], acc[r][c], 0, 0, 0);
        __syncthreads();
    }

    // phase 2a: q -> qs (with bias), x2 residual -> xr (coalesced)
    float b2[2];
#pragma unroll
    for (int c = 0; c < 2; ++c) b2[c] = qbias[n0 + wn + c * 16 + lm];
#pragma unroll
    for (int r = 0; r < 3; ++r)
#pragma unroll
        for (int i = 0; i < 4; ++i)
#pragma unroll
            for (int c = 0; c < 2; ++c)
                qs[(wm + r * 16 + lq * 4 + i) * 68 + wn + c * 16 + lm] = acc[r][c][i] + b2[c];
    {
        int c2 = t >> 2, rr = t & 3;
        const float* xp = x2 + chan0 + (long)(n0 + c2) * HW2 + pix0 + rr * 192;
#pragma unroll
        for (int q = 0; q < 6; ++q) {
            float4 v = *(const float4*)(xp + q * 4);
            xr[(rr * 24 + q * 4 + 0) * 68 + c2] = v.x;
            xr[(rr * 24 + q * 4 + 1) * 68 + c2] = v.y;
            xr[(rr * 24 + q * 4 + 2) * 68 + c2] = v.z;
            xr[(rr * 24 + q * 4 + 3) * 68 + c2] = v.w;
        }
    }
    __syncthreads();

    // phase 2b: per-thread one channel, 24 pixels; KtV column in registers
    int c = t & 63, g = t >> 6;
    int gc = n0 + c;
    int hd = gc >> 5;
    int jloc = gc & 31;
    int ihome = c & 32;
    const float* kt = ktv + ((long)(win * 8 + hd) * 32) * 32 + jloc;
    float kreg[32];
#pragma unroll
    for (int i = 0; i < 32; ++i) kreg[i] = kt[i * 32];
    long mrow = (long)b * HW2 + (long)(hh0 + g) * 192 + wx * 24;
    for (int pp = 0; pp < 24; ++pp) {
        int p = g * 24 + pp;
        float o = 0.f;
#pragma unroll
        for (int i = 0; i < 32; ++i) o += qs[p * 68 + ihome + i] * kreg[i];
        qf[(mrow + pp) * 256 + gc] = xr[p * 68 + c] + o;
    }
}

// ---------------------------------------------------------------------------
__device__ __forceinline__ float blocksum(float v, float* sb)
{
#pragma unroll
    for (int o = 32; o > 0; o >>= 1) v += __shfl_down(v, o, 64);
    int w = threadIdx.x >> 6;
    if ((threadIdx.x & 63) == 0) sb[w] = v;
    __syncthreads();
    float r = sb[0] + sb[1] + sb[2] + sb[3];
    __syncthreads();
    return r;
}

__global__ __launch_bounds__(256) void ln_plain(
    const float* __restrict__ in, float* __restrict__ out,
    const float* __restrict__ g, const float* __restrict__ b)
{
    __shared__ float sb[4];
    long m = blockIdx.x;
    int t = threadIdx.x;
    float x = in[m * 256 + t];
    float mean = blocksum(x, sb) * (1.0f / 256.0f);
    float d = x - mean;
    float var = blocksum(d * d, sb) * (1.0f / 256.0f);
    out[m * 256 + t] = d * rsqrtf(var + 1e-5f) * g[t] + b[t];
}

// ---------------------------------------------------------------------------
__global__ __launch_bounds__(256) void ktv_kernel(
    const u16* __restrict__ kb, const u16* __restrict__ vb,
    float* __restrict__ ktv)
{
    int blk = blockIdx.x;          // win*8 + head
    int win = blk >> 3, hd = blk & 7;
    int b = win >> 6, wy = (win >> 3) & 7, wx = win & 7;
    __shared__ float ks[144][33];
    __shared__ float vs[144][33];
    int t = threadIdx.x;
#pragma unroll
    for (int it = 0; it < 18; ++it) {
        int idx = t + it * 256;
        int p = idx >> 5, c = idx & 31;
        int py = p / 12, px = p % 12;
        long m = (long)b * HW1 + (long)(wy * 12 + py) * 96 + wx * 12 + px;
        ks[p][c] = bf2f(kb[m * 256 + hd * 32 + c]);
        vs[p][c] = bf2f(vb[m * 256 + hd * 32 + c]);
    }
    __syncthreads();
    int i = t >> 3, j0 = (t & 7) * 4;
    float acc[4] = {0.f, 0.f, 0.f, 0.f};
    for (int p = 0; p < 144; ++p) {
        float kv = ks[p][i];
#pragma unroll
        for (int jj = 0; jj < 4; ++jj) acc[jj] += kv * vs[p][j0 + jj];
    }
    long ob = ((long)blk * 32 + i) * 32 + j0;
#pragma unroll
    for (int jj = 0; jj < 4; ++jj) ktv[ob + jj] = acc[jj];
}

// ---------------------------------------------------------------------------
__device__ __forceinline__ float pe4(int t, float e)
{
    if (t == 0) return sinf(e);
    if (t == 1) return cosf(e);
    if (t == 2) return sinf(e * 0.01f);
    return cosf(e * 0.01f);
}

__global__ __launch_bounds__(256) void pool_q_k(
    const float* __restrict__ x2, float* __restrict__ qg)
{
    int blk = blockIdx.x;   // b*64 + gy*8 + gx
    int b = blk >> 6, gy = (blk >> 3) & 7, gx = blk & 7;
    int c = threadIdx.x;
    const float* p = x2 + ((long)(b * 256 + c) * 192 + gy * 24) * 192 + gx * 24;
    float s = 0.f;
    for (int i = 0; i < 24; ++i) {
        const float* pr = p + i * 192;
        for (int j = 0; j < 24; ++j) s += pr[j];
    }
    s *= (1.0f / 576.0f);
    const float TWO_PI = 6.283185307179586f;
    float pos;
    if (gy < 4) pos = pe4(gy,     (gx + 1) * (TWO_PI / (8.0f + 1e-5f)));
    else        pos = pe4(gy - 4, (c + 1)  * (TWO_PI / (256.0f + 1e-5f)));
    qg[(long)blk * 256 + c] = s + pos;
}

__global__ __launch_bounds__(256) void pool_k_k(
    const float* __restrict__ x1, float* __restrict__ kg)
{
    int blk = blockIdx.x;
    int b = blk >> 6, gy = (blk >> 3) & 7, gx = blk & 7;
    const float TWO_PI = 6.283185307179586f;
    for (int c = threadIdx.x; c < 512; c += 256) {
        const float* p = x1 + ((long)(b * 512 + c) * 96 + gy * 12) * 96 + gx * 12;
        float s = 0.f;
        for (int i = 0; i < 12; ++i) {
            const float* pr = p + i * 96;
            for (int j = 0; j < 12; ++j) s += pr[j];
        }
        s *= (1.0f / 144.0f);
        float pos;
        if (gy < 4) pos = pe4(gy,     (gx + 1) * (TWO_PI / (8.0f + 1e-5f)));
        else        pos = pe4(gy - 4, (c + 1)  * (TWO_PI / (512.0f + 1e-5f)));
        kg[(long)blk * 512 + c] = s + pos;
    }
}

// ---------------------------------------------------------------------------
template<int EPI>
__global__ __launch_bounds__(256) void gemm64(
    const float* __restrict__ A, const float* __restrict__ Bm,
    const float* __restrict__ bias, float* __restrict__ C,
    int N, int K, int ldA)
{
    constexpr int BK = 16;
    __shared__ float As[BK][68];
    __shared__ float Bs[BK][68];
    const int tid = threadIdx.x;
    const int m0 = blockIdx.y * 64;
    const int n0 = blockIdx.x * 64;
    const int tm = (tid >> 4) << 2;
    const int tn = (tid & 15) << 2;
    float acc[4][4] = {};
    for (int k0 = 0; k0 < K; k0 += BK) {
#pragma unroll
        for (int it = 0; it < 4; ++it) {
            int idx = tid + it * 256;
            int my = idx >> 4, kx = idx & 15;
            As[kx][my] = A[(long)(m0 + my) * ldA + (k0 + kx)];
        }
#pragma unroll
        for (int it = 0; it < 4; ++it) {
            int idx = tid + it * 256;
            int ky = idx >> 6, nx = idx & 63;
            Bs[ky][nx] = Bm[(long)(k0 + ky) * N + (n0 + nx)];
        }
        __syncthreads();
#pragma unroll
        for (int kk = 0; kk < BK; ++kk) {
            float a[4], b[4];
#pragma unroll
            for (int i = 0; i < 4; ++i) a[i] = As[kk][tm + i];
#pragma unroll
            for (int j = 0; j < 4; ++j) b[j] = Bs[kk][tn + j];
#pragma unroll
            for (int i = 0; i < 4; ++i)
#pragma unroll
                for (int j = 0; j < 4; ++j) acc[i][j] += a[i] * b[j];
        }
        __syncthreads();
    }
#pragma unroll
    for (int i = 0; i < 4; ++i) {
        long row = (long)(m0 + tm + i) * N;
#pragma unroll
        for (int j = 0; j < 4; ++j) {
            float v = acc[i][j] + bias[n0 + tn + j];
            if (EPI == 1) v = gelu_exact(v);
            C[row + n0 + tn + j] = v;
        }
    }
}

// ---------------------------------------------------------------------------
__global__ __launch_bounds__(256) void gattn(
    const float* __restrict__ qg2, const float* __restrict__ kg2,
    const float* __restrict__ vg, float* __restrict__ og)
{
    __shared__ float qh[64][33], kh[64][33], vh[64][33];
    __shared__ float S[64][65];
    __shared__ float rinv[64];
    int blk = blockIdx.x;
    int b = blk >> 3, hd = blk & 7;
    int t = threadIdx.x;
#pragma unroll
    for (int it = 0; it < 8; ++it) {
        int idx = t + it * 256;
        int n = idx >> 5, i = idx & 31;
        long src = (long)(b * 64 + n) * 256 + hd * 32 + i;
        qh[n][i] = qg2[src];
        kh[n][i] = kg2[src];
        vh[n][i] = vg[src];
    }
    __syncthreads();
    int r = t >> 2, c0 = (t & 3) * 16;
    for (int c = c0; c < c0 + 16; ++c) {
        float s = 0.f;
#pragma unroll
        for (int i = 0; i < 32; ++i) s += qh[r][i] * kh[c][i];
        S[r][c] = s;
    }
    __syncthreads();
    if (t < 64) {
        float mx = -1e30f;
        for (int c = 0; c < 64; ++c) mx = fmaxf(mx, S[t][c]);
        float sm = 0.f;
        for (int c = 0; c < 64; ++c) {
            float e = expf(S[t][c] - mx);
            S[t][c] = e;
            sm += e;
        }
        rinv[t] = 1.0f / sm;
    }
    __syncthreads();
    int n = t >> 2, j0 = (t & 3) * 8;
    float inv = rinv[n];
    for (int j = j0; j < j0 + 8; ++j) {
        float s = 0.f;
        for (int c = 0; c < 64; ++c) s += S[n][c] * vh[c][j];
        og[(long)(b * 64 + n) * 256 + hd * 32 + j] = s * inv;
    }
}

// ---------------------------------------------------------------------------
// hln = LN(qf + bilinear_ac(og, 8->192)), bf16 out. Wave-per-row, no barriers.
// ---------------------------------------------------------------------------
__global__ __launch_bounds__(256) void ln_h2(
    const float* __restrict__ qf, const float* __restrict__ og,
    u16* __restrict__ hln, const float* __restrict__ g,
    const float* __restrict__ bb)
{
    int w = threadIdx.x >> 6, lane = threadIdx.x & 63;
    long m = (long)blockIdx.x * 4 + w;
    int b = (int)(m / HW2), hw = (int)(m % HW2);
    int hh = hw / 192, ww = hw % 192;
    int c0 = lane * 4;
    float fy = hh * (7.0f / 191.0f);
    int y0 = (int)fy; int y1 = min(y0 + 1, 7); float wy = fy - y0;
    float fx = ww * (7.0f / 191.0f);
    int x0 = (int)fx; int x1 = min(x0 + 1, 7); float wxx = fx - x0;
    const float* base = og + (long)b * 64 * 256 + c0;
    float4 c00 = *(const float4*)(base + (y0 * 8 + x0) * 256);
    float4 c01 = *(const float4*)(base + (y0 * 8 + x1) * 256);
    float4 c10 = *(const float4*)(base + (y1 * 8 + x0) * 256);
    float4 c11 = *(const float4*)(base + (y1 * 8 + x1) * 256);
    float w00 = (1.f - wy) * (1.f - wxx), w01 = (1.f - wy) * wxx;
    float w10 = wy * (1.f - wxx),         w11 = wy * wxx;
    float4 xv = *(const float4*)(qf + m * 256 + c0);
    xv.x += w00 * c00.x + w01 * c01.x + w10 * c10.x + w11 * c11.x;
    xv.y += w00 * c00.y + w01 * c01.y + w10 * c10.y + w11 * c11.y;
    xv.z += w00 * c00.z + w01 * c01.z + w10 * c10.z + w11 * c11.z;
    xv.w += w00 * c00.w + w01 * c01.w + w10 * c10.w + w11 * c11.w;
    float s  = xv.x + xv.y + xv.z + xv.w;
    float s2 = xv.x * xv.x + xv.y * xv.y + xv.z * xv.z + xv.w * xv.w;
#pragma unroll
    for (int o = 32; o > 0; o >>= 1) {
        s  += __shfl_xor(s,  o, 64);
        s2 += __shfl_xor(s2, o, 64);
    }
    float mean = s * (1.0f / 256.0f);
    float var  = s2 * (1.0f / 256.0f) - mean * mean;
    float rs   = rsqrtf(var + 1e-5f);
    float4 g4 = *(const float4*)(g + c0);
    float4 b4 = *(const float4*)(bb + c0);
    ushort4 o4;
    o4.x = (u16)f2bf((xv.x - mean) * rs * g4.x + b4.x);
    o4.y = (u16)f2bf((xv.y - mean) * rs * g4.y + b4.y);
    o4.z = (u16)f2bf((xv.z - mean) * rs * g4.z + b4.z);
    o4.w = (u16)f2bf((xv.w - mean) * rs * g4.w + b4.w);
    *(ushort4*)(hln + m * 256 + c0) = o4;
}

// ---------------------------------------------------------------------------
// out = LN(mlp + bilinear_ac(sc, 96->192)) -> NCHW, LDS transpose for writes.
// ---------------------------------------------------------------------------
__global__ __launch_bounds__(256) void final_k2(
    const float* __restrict__ mlp, const float* __restrict__ sc,
    const float* __restrict__ g, const float* __restrict__ bb,
    float* __restrict__ out)
{
    __shared__ float lnb[32][258];
    int blk = blockIdx.x;              // b*1152 + hh*6 + strip
    int b = blk / 1152;
    int rem = blk - b * 1152;
    int hh = rem / 6, ww0 = (rem - (rem / 6) * 6) * 32;
    int wv = threadIdx.x >> 6, lane = threadIdx.x & 63;
    int c0 = lane * 4;
    float4 g4 = *(const float4*)(g + c0);
    float4 b4 = *(const float4*)(bb + c0);
    float fy = hh * (95.0f / 191.0f);
    int y0 = (int)fy; int y1 = min(y0 + 1, 95); float wy = fy - y0;
    const float* scb = sc + (long)b * 9216 * 256 + c0;
#pragma unroll
    for (int i = 0; i < 8; ++i) {
        int p = wv * 8 + i;
        int ww = ww0 + p;
        float fx = ww * (95.0f / 191.0f);
        int x0 = (int)fx; int x1 = min(x0 + 1, 95); float wx = fx - x0;
        float4 c00 = *(const float4*)(scb + (long)(y0 * 96 + x0) * 256);
        float4 c01 = *(const float4*)(scb + (long)(y0 * 96 + x1) * 256);
        float4 c10 = *(const float4*)(scb + (long)(y1 * 96 + x0) * 256);
        float4 c11 = *(const float4*)(scb + (long)(y1 * 96 + x1) * 256);
        long m = ((long)b * 192 + hh) * 192 + ww;
        float4 xv = *(const float4*)(mlp + m * 256 + c0);
        float w00 = (1.f - wy) * (1.f - wx), w01 = (1.f - wy) * wx;
        float w10 = wy * (1.f - wx),         w11 = wy * wx;
        xv.x += w00 * c00.x + w01 * c01.x + w10 * c10.x + w11 * c11.x;
        xv.y += w00 * c00.y + w01 * c01.y + w10 * c10.y + w11 * c11.y;
        xv.z += w00 * c00.z + w01 * c01.z + w10 * c10.z + w11 * c11.z;
        xv.w += w00 * c00.w + w01 * c01.w + w10 * c10.w + w11 * c11.w;
        float s  = xv.x + xv.y + xv.z + xv.w;
        float s2 = xv.x * xv.x + xv.y * xv.y + xv.z * xv.z + xv.w * xv.w;
#pragma unroll
        for (int o = 32; o > 0; o >>= 1) {
            s  += __shfl_xor(s,  o, 64);
            s2 += __shfl_xor(s2, o, 64);
        }
        float mean = s * (1.0f / 256.0f);
        float var  = s2 * (1.0f / 256.0f) - mean * mean;
        float rs   = rsqrtf(var + 1e-5f);
        lnb[p][c0 + 0] = (xv.x - mean) * rs * g4.x + b4.x;
        lnb[p][c0 + 1] = (xv.y - mean) * rs * g4.y + b4.y;
        lnb[p][c0 + 2] = (xv.z - mean) * rs * g4.z + b4.z;
        lnb[p][c0 + 3] = (xv.w - mean) * rs * g4.w + b4.w;
    }
    __syncthreads();
    int tw = threadIdx.x & 31, cg = threadIdx.x >> 5;
#pragma unroll
    for (int cc = 0; cc < 32; ++cc) {
        int c = cg * 32 + cc;
        out[((long)(b * 256 + c) * 192 + hh) * 192 + ww0 + tw] = lnb[tw][c];
    }
}

// ---------------------------------------------------------------------------
extern "C" void kernel_launch(void* const* d_in, const int* in_sizes, int n_in,
                              void* d_out, int out_size, void* d_ws, size_t ws_size,
                              hipStream_t stream)
{
    const float* x1     = (const float*)d_in[0];
    const float* x2     = (const float*)d_in[1];
    const float* q_w    = (const float*)d_in[2];
    const float* q_b    = (const float*)d_in[3];
    const float* k_w    = (const float*)d_in[4];
    const float* k_b    = (const float*)d_in[5];
    const float* v_w    = (const float*)d_in[6];
    const float* v_b    = (const float*)d_in[7];
    const float* q2_w   = (const float*)d_in[8];
    const float* q2_b   = (const float*)d_in[9];
    const float* k2_w   = (const float*)d_in[10];
    const float* k2_b   = (const float*)d_in[11];
    const float* v2_w   = (const float*)d_in[12];
    const float* v2_b   = (const float*)d_in[13];
    const float* proj_w = (const float*)d_in[14];
    const float* proj_b = (const float*)d_in[15];
    const float* proj_g = (const float*)d_in[16];
    const float* proj_bt= (const float*)d_in[17];
    const float* n1_g   = (const float*)d_in[18];
    const float* n1_b   = (const float*)d_in[19];
    const float* n2_g   = (const float*)d_in[20];
    const float* n2_b   = (const float*)d_in[21];
    const float* fc1_w  = (const float*)d_in[22];
    const float* fc1_b  = (const float*)d_in[23];
    const float* fc2_w  = (const float*)d_in[24];
    const float* fc2_b  = (const float*)d_in[25];
    float* out = (float*)d_out;

    // workspace carve (bytes), total ~175 MB
    char* p = (char*)d_ws;
    float* sc   = (float*)p;  p += M1 * 256 * 4;        // 18.9 MB
    float* qfb  = (float*)p;  p += M2 * 256 * 4;        // 75.5 MB (qf, later mlp out)
    float* ktv  = (float*)p;  p += 1024L * 32 * 32 * 4; // 4.2 MB
    u16*   hln  = (u16*)p;    p += M2 * 256 * 2;        // 37.7 MB
    u16*   h1c  = (u16*)p;    p += 18432L * 512 * 2;    // 18.9 MB
    u16*   kb16 = (u16*)p;    p += M1 * 256 * 2;        // 9.4 MB
    u16*   vb16 = (u16*)p;    p += M1 * 256 * 2;        // 9.4 MB
    float* qg   = (float*)p;  p += 128L * 256 * 4;
    float* kg   = (float*)p;  p += 128L * 512 * 4;
    float* qg2  = (float*)p;  p += 128L * 256 * 4;
    float* kg2  = (float*)p;  p += 128L * 256 * 4;
    float* vgb  = (float*)p;  p += 128L * 256 * 4;
    float* ogb  = (float*)p;  p += 128L * 256 * 4;

    dim3 blk(256);

    // 1) sc = LN(x1n @ proj_w + proj_b)
    gemm_at<float><<<dim3(4, 144), blk, 0, stream>>>(
        x1, proj_w, proj_b, sc, proj_w, proj_b, sc, 512, 9216, 9216, 512L * 9216);
    ln_plain<<<dim3(18432), blk, 0, stream>>>(sc, sc, proj_g, proj_bt);

    // 2) k & v projections fused (split-N), bf16 out
    gemm_at<u16><<<dim3(8, 144), blk, 0, stream>>>(
        x1, k_w, k_b, kb16, v_w, v_b, vb16, 512, 9216, 9216, 512L * 9216);

    // 3) per (window, head) K^T V
    ktv_kernel<<<dim3(1024), blk, 0, stream>>>(kb16, vb16, ktv);

    // 4) fused q-projection + window attention + residual
    qproj_qf<<<dim3(4, 768), blk, 0, stream>>>(x2, q_w, q_b, ktv, qfb);

    // 5) pooled q/k with (faithfully permuted) sine pos
    pool_q_k<<<dim3(128), blk, 0, stream>>>(x2, qg);
    pool_k_k<<<dim3(128), blk, 0, stream>>>(x1, kg);

    // 6-8) global projections (tiny, fp32)
    gemm64<0><<<dim3(4, 2), blk, 0, stream>>>(qg, q2_w, q2_b, qg2, 256, 256, 256);
    gemm64<0><<<dim3(4, 2), blk, 0, stream>>>(kg, k2_w, k2_b, kg2, 256, 512, 512);
    gemm64<0><<<dim3(4, 2), blk, 0, stream>>>(kg, v2_w, v2_b, vgb, 256, 512, 512);

    // 9) global softmax attention
    gattn<<<dim3(16), blk, 0, stream>>>(qg2, kg2, vgb, ogb);

    // 10) hln = LN(qf + upsample(og)) -> bf16
    ln_h2<<<dim3(18432), blk, 0, stream>>>(qfb, ogb, hln, n1_g, n1_b);

    // 11-12) MLP, chunked x4 over rows; bf16 A operands; h1 bf16
    for (int c4 = 0; c4 < 4; ++c4) {
        const u16* aoff = hln + (long)c4 * 18432 * 256;
        float*     coff = qfb + (long)c4 * 18432 * 256;
        gemm_bf16rm<1, u16><<<dim3(8, 144), blk, 0, stream>>>(
            aoff, fc1_w, fc1_b, h1c, 512, 256, 256);
        gemm_bf16rm<0, float><<<dim3(4, 144), blk, 0, stream>>>(
            h1c, fc2_w, fc2_b, coff, 256, 512, 512);
    }

    // 13) out = LN(mlp + upsample(sc)) -> NCHW
    final_k2<<<dim3(2304), blk, 0, stream>>>(qfb, sc, n2_g, n2_b, out);
}

// Round 4
// 717.464 us; speedup vs baseline: 2.3681x; 1.0874x over previous
//
#include <hip/hip_runtime.h>
#include <math.h>

// ---------------------------------------------------------------------------
// TransFusion3: B=2, C1=512, H1=W1=96, C2=256, H2=W2=192, D=256, NH=8, hd=32,
// WQ=24x24, WK=12x12. 64 windows per image; q-window i aligns with k-window i.
// ---------------------------------------------------------------------------

#define HW1 9216L      // 96*96
#define HW2 36864L     // 192*192
#define M1  18432L     // 2*96*96
#define M2  73728L     // 2*192*192

typedef __attribute__((ext_vector_type(8))) short short8;
typedef __attribute__((ext_vector_type(4))) float f32x4;
typedef unsigned short u16;

__device__ __forceinline__ short f2bf(float f)
{
    unsigned u = __builtin_bit_cast(unsigned, f);
    u = (u + 0x7fff + ((u >> 16) & 1)) >> 16;   // RNE
    return (short)u;
}
__device__ __forceinline__ float bf2f(u16 u)
{
    unsigned x = ((unsigned)u) << 16;
    return __builtin_bit_cast(float, x);
}
__device__ __forceinline__ float gelu_exact(float v)
{
    return 0.5f * v * (1.0f + erff(v * 0.70710678118654752f));
}

// ---------------------------------------------------------------------------
// gemm_at: C[m][n] = sum_k A(k,m)*B[k][n] + bias[n]; A fp32 K-major (NCHW),
// outputs 256-wide; split-N at 256 (blocks with n0>=256 use B2/b2/C2).
// BM=128, BN=128, BK=32; mfma 16x16x32 bf16; TC=float or u16 (LDS repack).
// ---------------------------------------------------------------------------
template<typename TC>
__global__ __launch_bounds__(256) void gemm_at(
    const float* __restrict__ A,
    const float* __restrict__ B1, const float* __restrict__ b1, TC* __restrict__ C1,
    const float* __restrict__ B2, const float* __restrict__ b2, TC* __restrict__ C2,
    int K, int ldA, int hwA, long batA)
{
    __shared__ short pool[17408];          // As[128][40] Bs[128][40] | ob[128][136]
    short* As = pool;
    short* Bs = pool + 128 * 40;
    const int tid = threadIdx.x;
    const int m0 = blockIdx.y * 128;
    int n0 = blockIdx.x * 128;
    const float* Bm; const float* bias; TC* C;
    if (n0 < 256) { Bm = B1; bias = b1; C = C1; }
    else          { Bm = B2; bias = b2; C = C2; n0 -= 256; }
    const long aBase = (long)(m0 / hwA) * batA + (long)(m0 % hwA);

    const int w = tid >> 6, lane = tid & 63;
    const int wm = (w & 1) * 64, wn = (w >> 1) * 64;
    const int lm = lane & 15, lq = lane >> 4;

    f32x4 acc[4][4] = {};

    for (int k0 = 0; k0 < K; k0 += 32) {
        {   // stage A: 128 m x 32 k
            int ml = tid & 127, kh = tid >> 7;         // kh in {0,1}: 16 k's
            const float* Ap = A + aBase + ml + (long)(k0 + kh * 16) * ldA;
            float v[16];
#pragma unroll
            for (int j = 0; j < 16; ++j) v[j] = Ap[(long)j * ldA];
            short8 s0, s1;
#pragma unroll
            for (int j = 0; j < 8; ++j) { s0[j] = f2bf(v[j]); s1[j] = f2bf(v[j + 8]); }
            *(short8*)&As[ml * 40 + kh * 16]     = s0;
            *(short8*)&As[ml * 40 + kh * 16 + 8] = s1;
        }
        {   // stage B: 128 n x 32 k (weights row-major [K][256])
            int nl = tid & 127, kc = tid >> 7;         // kc in {0,1}: 16 k's
            const float* Bp = Bm + (long)(k0 + kc * 16) * 256 + n0 + nl;
            short8 s0, s1;
#pragma unroll
            for (int j = 0; j < 8; ++j) {
                s0[j] = f2bf(Bp[(long)j * 256]);
                s1[j] = f2bf(Bp[(long)(j + 8) * 256]);
            }
            *(short8*)&Bs[nl * 40 + kc * 16]     = s0;
            *(short8*)&Bs[nl * 40 + kc * 16 + 8] = s1;
        }
        __syncthreads();
        short8 af[4], bfr[4];
#pragma unroll
        for (int r = 0; r < 4; ++r) af[r] = *(short8*)&As[(wm + r * 16 + lm) * 40 + lq * 8];
#pragma unroll
        for (int c = 0; c < 4; ++c) bfr[c] = *(short8*)&Bs[(wn + c * 16 + lm) * 40 + lq * 8];
#pragma unroll
        for (int r = 0; r < 4; ++r)
#pragma unroll
            for (int c = 0; c < 4; ++c)
                acc[r][c] = __builtin_amdgcn_mfma_f32_16x16x32_bf16(af[r], bfr[c], acc[r][c], 0, 0, 0);
        __syncthreads();
    }

    if constexpr (sizeof(TC) == 4) {
#pragma unroll
        for (int r = 0; r < 4; ++r)
#pragma unroll
            for (int i = 0; i < 4; ++i) {
                long row = (long)(m0 + wm + r * 16 + lq * 4 + i) * 256;
#pragma unroll
                for (int c = 0; c < 4; ++c) {
                    int col = n0 + wn + c * 16 + lm;
                    ((float*)C)[row + col] = acc[r][c][i] + bias[col];
                }
            }
    } else {
        short* ob = pool;   // [128][136]
#pragma unroll
        for (int r = 0; r < 4; ++r)
#pragma unroll
            for (int i = 0; i < 4; ++i) {
                int row = wm + r * 16 + lq * 4 + i;
#pragma unroll
                for (int c = 0; c < 4; ++c) {
                    int jl = wn + c * 16 + lm;
                    ob[row * 136 + jl] = f2bf(acc[r][c][i] + bias[n0 + jl]);
                }
            }
        __syncthreads();
        int m = tid >> 1, half = (tid & 1) * 64;
        u16* Cp = (u16*)C + (long)(m0 + m) * 256 + n0 + half;
#pragma unroll
        for (int q = 0; q < 8; ++q)
            *(short8*)(Cp + q * 8) = *(short8*)&ob[m * 136 + half + q * 8];
    }
}

// ---------------------------------------------------------------------------
// gemm_bf16rm: A bf16 row-major [M][ldA], B fp32 [K][N]. BM=128,BN=128,BK=64.
// EPI: 0 none, 1 exact gelu. bf16 output via LDS repack.
// ---------------------------------------------------------------------------
template<int EPI>
__global__ __launch_bounds__(256) void gemm_bf16rm(
    const u16* __restrict__ A, const float* __restrict__ Bm,
    const float* __restrict__ bias, u16* __restrict__ C,
    int N, int K, int ldA)
{
    __shared__ short pool[18432];  // As[128][72] Bs[128][72] | ob[128][136]
    short* As = pool;
    short* Bs = pool + 128 * 72;
    const int tid = threadIdx.x;
    const int m0 = blockIdx.y * 128;
    const int n0 = blockIdx.x * 128;
    const int w = tid >> 6, lane = tid & 63;
    const int wm = (w & 1) * 64, wn = (w >> 1) * 64;
    const int lm = lane & 15, lq = lane >> 4;

    f32x4 acc[4][4] = {};

    for (int k0 = 0; k0 < K; k0 += 64) {
        {   // stage A: 128 rows x 64 k, straight bf16 copy
            int m = tid >> 1, kh = (tid & 1) * 32;
            const u16* Ap = A + (long)(m0 + m) * ldA + k0 + kh;
#pragma unroll
            for (int q = 0; q < 4; ++q)
                *(short8*)&As[m * 72 + kh + q * 8] = *(const short8*)(Ap + q * 8);
        }
        {   // stage B: 128 n x 64 k
            int nl = tid & 127, kc = (tid >> 7) * 32;
            const float* Bp = Bm + (long)(k0 + kc) * N + n0 + nl;
#pragma unroll
            for (int jc = 0; jc < 4; ++jc) {
                short8 s;
#pragma unroll
                for (int j = 0; j < 8; ++j) s[j] = f2bf(Bp[(long)(jc * 8 + j) * N]);
                *(short8*)&Bs[nl * 72 + kc + jc * 8] = s;
            }
        }
        __syncthreads();
#pragma unroll
        for (int kk = 0; kk < 64; kk += 32) {
            short8 af[4], bfr[4];
#pragma unroll
            for (int r = 0; r < 4; ++r) af[r] = *(short8*)&As[(wm + r * 16 + lm) * 72 + kk + lq * 8];
#pragma unroll
            for (int c = 0; c < 4; ++c) bfr[c] = *(short8*)&Bs[(wn + c * 16 + lm) * 72 + kk + lq * 8];
#pragma unroll
            for (int r = 0; r < 4; ++r)
#pragma unroll
                for (int c = 0; c < 4; ++c)
                    acc[r][c] = __builtin_amdgcn_mfma_f32_16x16x32_bf16(af[r], bfr[c], acc[r][c], 0, 0, 0);
        }
        __syncthreads();
    }

    short* ob = pool;   // [128][136]
#pragma unroll
    for (int r = 0; r < 4; ++r)
#pragma unroll
        for (int i = 0; i < 4; ++i) {
            int row = wm + r * 16 + lq * 4 + i;
#pragma unroll
            for (int c = 0; c < 4; ++c) {
                int jl = wn + c * 16 + lm;
                float v = acc[r][c][i] + bias[n0 + jl];
                if (EPI == 1) v = gelu_exact(v);
                ob[row * 136 + jl] = f2bf(v);
            }
        }
    __syncthreads();
    int m = tid >> 1, half = (tid & 1) * 64;
    u16* Cp = C + (long)(m0 + m) * N + n0 + half;
#pragma unroll
    for (int q = 0; q < 8; ++q)
        *(short8*)(Cp + q * 8) = *(short8*)&ob[m * 136 + half + q * 8];
}

// ---------------------------------------------------------------------------
// wattn_ln: fully fused  hln = LN( x2 + (x2@q_w + q_b)@KtV + up(og) ) -> bf16.
// Block = one window 2-row strip (48 px) x ALL 256 channels. grid(1536).
// Phase 1: projection GEMM (x2 staged once, doubles as residual).
// Phase 2: per-head 48x32 @ 32x32 MFMA vs KtV (bf16, LDS).
// Phase 3: +residual +og bilinear, LN across channels, bf16 store.
// ---------------------------------------------------------------------------
__global__ __launch_bounds__(256) void wattn_ln(
    const float* __restrict__ x2, const float* __restrict__ qw,
    const float* __restrict__ qbias, const float* __restrict__ ktv,
    const float* __restrict__ og, u16* __restrict__ hln,
    const float* __restrict__ n1g, const float* __restrict__ n1b)
{
    __shared__ short pool[35584];            // 71168 B
    short* As  = pool;                       // [48][264] bf16 x2 (resident)
    short* qs  = pool + 12672;               // [48][264] bf16 q; Bs aliases here
    short* Bs  = qs;                         // [256][40] during phase 1
    short* kvs = pool + 25344;               // [8][32][40] ktv bf16 (n-major)

    const int t = threadIdx.x;
    const int blk = blockIdx.x;              // win*12 + strip
    const int strip = blk % 12, win = blk / 12;
    const int b = win >> 6, wy = (win >> 3) & 7, wxw = win & 7;
    const int hh0 = wy * 24 + strip * 2;
    const long chan0 = (long)b * 256 * HW2;
    const long pix0  = (long)hh0 * 192 + wxw * 24;

    const int w = t >> 6, lane = t & 63;
    const int lm = lane & 15, lq = lane >> 4;

    // ---- stage kvs: ktv[h][k][n] -> bf16 kvs[h][n][k] ----
    {
        int h = t >> 5, n = t & 31;
        const float* kp = ktv + ((long)(win * 8 + h) * 32) * 32 + n;
#pragma unroll
        for (int jc = 0; jc < 4; ++jc) {
            short8 s;
#pragma unroll
            for (int j = 0; j < 8; ++j) s[j] = f2bf(kp[(jc * 8 + j) * 32]);
            *(short8*)&kvs[(h * 32 + n) * 40 + jc * 8] = s;
        }
    }
    // ---- stage As: all 48 px x 256 ch of x2 ----
#pragma unroll
    for (int kc = 0; kc < 8; ++kc) {
        int k = kc * 32 + (t >> 3);
        int pxg = (t & 7) * 6;
        int rr = pxg / 24, cc = pxg % 24;
        const float* Ap = x2 + chan0 + (long)k * HW2 + pix0 + rr * 192 + cc;
#pragma unroll
        for (int j = 0; j < 6; ++j)
            As[(pxg + j) * 264 + k] = f2bf(Ap[j]);
    }

    // ---- phase 1: q = x2 @ q_w ----
    f32x4 acc[3][4] = {};
    for (int kc = 0; kc < 8; ++kc) {
        {   // stage B: 256 n x 32 k
            const float* Bp = qw + (long)(kc * 32) * 256 + t;
#pragma unroll
            for (int jc = 0; jc < 4; ++jc) {
                short8 s;
#pragma unroll
                for (int j = 0; j < 8; ++j) s[j] = f2bf(Bp[(long)(jc * 8 + j) * 256]);
                *(short8*)&Bs[t * 40 + jc * 8] = s;
            }
        }
        __syncthreads();
        short8 af[3], bfr[4];
#pragma unroll
        for (int r = 0; r < 3; ++r) af[r] = *(short8*)&As[(r * 16 + lm) * 264 + kc * 32 + lq * 8];
#pragma unroll
        for (int c = 0; c < 4; ++c) bfr[c] = *(short8*)&Bs[(w * 64 + c * 16 + lm) * 40 + lq * 8];
#pragma unroll
        for (int r = 0; r < 3; ++r)
#pragma unroll
            for (int c = 0; c < 4; ++c)
                acc[r][c] = __builtin_amdgcn_mfma_f32_16x16x32_bf16(af[r], bfr[c], acc[r][c], 0, 0, 0);
        __syncthreads();
    }
    // ---- q (+bias) -> qs bf16 (overwrites Bs region) ----
#pragma unroll
    for (int c = 0; c < 4; ++c) {
        float bv = qbias[w * 64 + c * 16 + lm];
#pragma unroll
        for (int r = 0; r < 3; ++r)
#pragma unroll
            for (int i = 0; i < 4; ++i)
                qs[(r * 16 + lq * 4 + i) * 264 + w * 64 + c * 16 + lm] = f2bf(acc[r][c][i] + bv);
    }
    __syncthreads();

    // ---- phase 2: o = q @ KtV per head (wave w -> heads 2w, 2w+1) ----
    f32x4 oacc[2][3][2] = {};
#pragma unroll
    for (int hl = 0; hl < 2; ++hl) {
        int h = w * 2 + hl;
        short8 af2[3], bfr2[2];
#pragma unroll
        for (int r = 0; r < 3; ++r) af2[r] = *(short8*)&qs[(r * 16 + lm) * 264 + h * 32 + lq * 8];
#pragma unroll
        for (int c = 0; c < 2; ++c) bfr2[c] = *(short8*)&kvs[(h * 32 + c * 16 + lm) * 40 + lq * 8];
#pragma unroll
        for (int r = 0; r < 3; ++r)
#pragma unroll
            for (int c = 0; c < 2; ++c)
                oacc[hl][r][c] = __builtin_amdgcn_mfma_f32_16x16x32_bf16(af2[r], bfr2[c], oacc[hl][r][c], 0, 0, 0);
    }

    // ---- phase 3a: x = residual + o + up(og) -> back into As (bf16) ----
    const float* ogb0 = og + (long)b * 64 * 256;
#pragma unroll
    for (int r = 0; r < 3; ++r)
#pragma unroll
        for (int i = 0; i < 4; ++i) {
            int p = r * 16 + lq * 4 + i;
            int hh = hh0 + (p / 24), ww = wxw * 24 + (p % 24);
            float fy = hh * (7.0f / 191.0f);
            int y0 = (int)fy; int y1 = min(y0 + 1, 7); float wyf = fy - y0;
            float fx = ww * (7.0f / 191.0f);
            int x0 = (int)fx; int x1 = min(x0 + 1, 7); float wxf = fx - x0;
            float w00 = (1.f - wyf) * (1.f - wxf), w01 = (1.f - wyf) * wxf;
            float w10 = wyf * (1.f - wxf),         w11 = wyf * wxf;
            const float* o00 = ogb0 + (y0 * 8 + x0) * 256;
            const float* o01 = ogb0 + (y0 * 8 + x1) * 256;
            const float* o10 = ogb0 + (y1 * 8 + x0) * 256;
            const float* o11 = ogb0 + (y1 * 8 + x1) * 256;
#pragma unroll
            for (int hl = 0; hl < 2; ++hl) {
                int h = w * 2 + hl;
#pragma unroll
                for (int c = 0; c < 2; ++c) {
                    int ch = h * 32 + c * 16 + lm;
                    float ogv = w00 * o00[ch] + w01 * o01[ch] + w10 * o10[ch] + w11 * o11[ch];
                    float x = bf2f((u16)As[p * 264 + ch]) + oacc[hl][r][c][i] + ogv;
                    As[p * 264 + ch] = f2bf(x);
                }
            }
        }
    __syncthreads();

    // ---- phase 3b: LN over 256 ch per pixel; wave w handles 12 px ----
    float4 g4 = *(const float4*)(n1g + lane * 4);
    float4 b4 = *(const float4*)(n1b + lane * 4);
#pragma unroll
    for (int pp = 0; pp < 12; ++pp) {
        int p = w * 12 + pp;
        ushort4 u4 = *(ushort4*)&As[p * 264 + lane * 4];
        float x0 = bf2f(u4.x), x1 = bf2f(u4.y), x2v = bf2f(u4.z), x3 = bf2f(u4.w);
        float s  = x0 + x1 + x2v + x3;
        float s2 = x0 * x0 + x1 * x1 + x2v * x2v + x3 * x3;
#pragma unroll
        for (int o = 32; o > 0; o >>= 1) {
            s  += __shfl_xor(s,  o, 64);
            s2 += __shfl_xor(s2, o, 64);
        }
        float mean = s * (1.0f / 256.0f);
        float var  = s2 * (1.0f / 256.0f) - mean * mean;
        float rs   = rsqrtf(var + 1e-5f);
        long m = (long)b * HW2 + (long)(hh0 + p / 24) * 192 + wxw * 24 + (p % 24);
        ushort4 o4;
        o4.x = (u16)f2bf((x0 - mean) * rs * g4.x + b4.x);
        o4.y = (u16)f2bf((x1 - mean) * rs * g4.y + b4.y);
        o4.z = (u16)f2bf((x2v - mean) * rs * g4.z + b4.z);
        o4.w = (u16)f2bf((x3 - mean) * rs * g4.w + b4.w);
        *(ushort4*)(hln + m * 256 + lane * 4) = o4;
    }
}

// ---------------------------------------------------------------------------
// LN over rows of 256 (fp32 in), bf16 out.
// ---------------------------------------------------------------------------
__global__ __launch_bounds__(256) void ln_sc(
    const float* __restrict__ in, u16* __restrict__ out,
    const float* __restrict__ g, const float* __restrict__ b)
{
    __shared__ float sb[4];
    long m = blockIdx.x;
    int t = threadIdx.x;
    float x = in[m * 256 + t];
    float v = x;
#pragma unroll
    for (int o = 32; o > 0; o >>= 1) v += __shfl_down(v, o, 64);
    int wv = t >> 6;
    if ((t & 63) == 0) sb[wv] = v;
    __syncthreads();
    float mean = (sb[0] + sb[1] + sb[2] + sb[3]) * (1.0f / 256.0f);
    __syncthreads();
    float d = x - mean;
    float v2 = d * d;
#pragma unroll
    for (int o = 32; o > 0; o >>= 1) v2 += __shfl_down(v2, o, 64);
    if ((t & 63) == 0) sb[wv] = v2;
    __syncthreads();
    float var = (sb[0] + sb[1] + sb[2] + sb[3]) * (1.0f / 256.0f);
    out[m * 256 + t] = (u16)f2bf(d * rsqrtf(var + 1e-5f) * g[t] + b[t]);
}

// ---------------------------------------------------------------------------
__global__ __launch_bounds__(256) void ktv_kernel(
    const u16* __restrict__ kb, const u16* __restrict__ vb,
    float* __restrict__ ktv)
{
    int blk = blockIdx.x;          // win*8 + head
    int win = blk >> 3, hd = blk & 7;
    int b = win >> 6, wy = (win >> 3) & 7, wx = win & 7;
    __shared__ float ks[144][33];
    __shared__ float vs[144][33];
    int t = threadIdx.x;
#pragma unroll
    for (int it = 0; it < 18; ++it) {
        int idx = t + it * 256;
        int p = idx >> 5, c = idx & 31;
        int py = p / 12, px = p % 12;
        long m = (long)b * HW1 + (long)(wy * 12 + py) * 96 + wx * 12 + px;
        ks[p][c] = bf2f(kb[m * 256 + hd * 32 + c]);
        vs[p][c] = bf2f(vb[m * 256 + hd * 32 + c]);
    }
    __syncthreads();
    int i = t >> 3, j0 = (t & 7) * 4;
    float acc[4] = {0.f, 0.f, 0.f, 0.f};
    for (int p = 0; p < 144; ++p) {
        float kv = ks[p][i];
#pragma unroll
        for (int jj = 0; jj < 4; ++jj) acc[jj] += kv * vs[p][j0 + jj];
    }
    long ob = ((long)blk * 32 + i) * 32 + j0;
#pragma unroll
    for (int jj = 0; jj < 4; ++jj) ktv[ob + jj] = acc[jj];
}

// ---------------------------------------------------------------------------
__device__ __forceinline__ float pe4(int t, float e)
{
    if (t == 0) return sinf(e);
    if (t == 1) return cosf(e);
    if (t == 2) return sinf(e * 0.01f);
    return cosf(e * 0.01f);
}

// pooled q: grid 3072 = win*24 + row; 256 ch threads; atomicAdd into qg
__global__ __launch_bounds__(256) void pool_q2(
    const float* __restrict__ x2, float* __restrict__ qg)
{
    int blk = blockIdx.x;
    int win = blk / 24, row = blk % 24;
    int b = win >> 6, gy = (win >> 3) & 7, gx = win & 7;
    int c = threadIdx.x;
    const float* p = x2 + ((long)(b * 256 + c) * 192 + gy * 24 + row) * 192 + gx * 24;
    float s = 0.f;
#pragma unroll
    for (int q = 0; q < 6; ++q) {
        float4 v = *(const float4*)(p + q * 4);
        s += v.x + v.y + v.z + v.w;
    }
    atomicAdd(qg + (long)win * 256 + c, s * (1.0f / 576.0f));
}

// pooled k: grid 1536 = win*12 + row; thread covers ch c and c+256
__global__ __launch_bounds__(256) void pool_k2(
    const float* __restrict__ x1, float* __restrict__ kg)
{
    int blk = blockIdx.x;
    int win = blk / 12, row = blk % 12;
    int b = win >> 6, gy = (win >> 3) & 7, gx = win & 7;
#pragma unroll
    for (int h = 0; h < 2; ++h) {
        int c = threadIdx.x + h * 256;
        const float* p = x1 + ((long)(b * 512 + c) * 96 + gy * 12 + row) * 96 + gx * 12;
        float s = 0.f;
#pragma unroll
        for (int q = 0; q < 3; ++q) {
            float4 v = *(const float4*)(p + q * 4);
            s += v.x + v.y + v.z + v.w;
        }
        atomicAdd(kg + (long)win * 512 + c, s * (1.0f / 144.0f));
    }
}

// add sine-pos (reference's permuted-shape call) to pooled qg/kg. grid 128.
__global__ __launch_bounds__(256) void posfix(
    float* __restrict__ qg, float* __restrict__ kg)
{
    int win = blockIdx.x;
    int gy = (win >> 3) & 7, gx = win & 7;
    int t = threadIdx.x;
    const float TWO_PI = 6.283185307179586f;
    {
        float pos;
        if (gy < 4) pos = pe4(gy,     (gx + 1) * (TWO_PI / (8.0f + 1e-5f)));
        else        pos = pe4(gy - 4, (t + 1)  * (TWO_PI / (256.0f + 1e-5f)));
        qg[(long)win * 256 + t] += pos;
    }
#pragma unroll
    for (int h = 0; h < 2; ++h) {
        int c = t + h * 256;
        float pos;
        if (gy < 4) pos = pe4(gy,     (gx + 1) * (TWO_PI / (8.0f + 1e-5f)));
        else        pos = pe4(gy - 4, (c + 1)  * (TWO_PI / (512.0f + 1e-5f)));
        kg[(long)win * 512 + c] += pos;
    }
}

// ---------------------------------------------------------------------------
template<int EPI>
__global__ __launch_bounds__(256) void gemm64(
    const float* __restrict__ A, const float* __restrict__ Bm,
    const float* __restrict__ bias, float* __restrict__ C,
    int N, int K, int ldA)
{
    constexpr int BK = 16;
    __shared__ float As[BK][68];
    __shared__ float Bs[BK][68];
    const int tid = threadIdx.x;
    const int m0 = blockIdx.y * 64;
    const int n0 = blockIdx.x * 64;
    const int tm = (tid >> 4) << 2;
    const int tn = (tid & 15) << 2;
    float acc[4][4] = {};
    for (int k0 = 0; k0 < K; k0 += BK) {
#pragma unroll
        for (int it = 0; it < 4; ++it) {
            int idx = tid + it * 256;
            int my = idx >> 4, kx = idx & 15;
            As[kx][my] = A[(long)(m0 + my) * ldA + (k0 + kx)];
        }
#pragma unroll
        for (int it = 0; it < 4; ++it) {
            int idx = tid + it * 256;
            int ky = idx >> 6, nx = idx & 63;
            Bs[ky][nx] = Bm[(long)(k0 + ky) * N + (n0 + nx)];
        }
        __syncthreads();
#pragma unroll
        for (int kk = 0; kk < BK; ++kk) {
            float a[4], b[4];
#pragma unroll
            for (int i = 0; i < 4; ++i) a[i] = As[kk][tm + i];
#pragma unroll
            for (int j = 0; j < 4; ++j) b[j] = Bs[kk][tn + j];
#pragma unroll
            for (int i = 0; i < 4; ++i)
#pragma unroll
                for (int j = 0; j < 4; ++j) acc[i][j] += a[i] * b[j];
        }
        __syncthreads();
    }
#pragma unroll
    for (int i = 0; i < 4; ++i) {
        long row = (long)(m0 + tm + i) * N;
#pragma unroll
        for (int j = 0; j < 4; ++j) {
            float v = acc[i][j] + bias[n0 + tn + j];
            if (EPI == 1) v = gelu_exact(v);
            C[row + n0 + tn + j] = v;
        }
    }
}

// ---------------------------------------------------------------------------
__global__ __launch_bounds__(256) void gattn(
    const float* __restrict__ qg2, const float* __restrict__ kg2,
    const float* __restrict__ vg, float* __restrict__ og)
{
    __shared__ float qh[64][33], kh[64][33], vh[64][33];
    __shared__ float S[64][65];
    __shared__ float rinv[64];
    int blk = blockIdx.x;
    int b = blk >> 3, hd = blk & 7;
    int t = threadIdx.x;
#pragma unroll
    for (int it = 0; it < 8; ++it) {
        int idx = t + it * 256;
        int n = idx >> 5, i = idx & 31;
        long src = (long)(b * 64 + n) * 256 + hd * 32 + i;
        qh[n][i] = qg2[src];
        kh[n][i] = kg2[src];
        vh[n][i] = vg[src];
    }
    __syncthreads();
    int r = t >> 2, c0 = (t & 3) * 16;
    for (int c = c0; c < c0 + 16; ++c) {
        float s = 0.f;
#pragma unroll
        for (int i = 0; i < 32; ++i) s += qh[r][i] * kh[c][i];
        S[r][c] = s;
    }
    __syncthreads();
    if (t < 64) {
        float mx = -1e30f;
        for (int c = 0; c < 64; ++c) mx = fmaxf(mx, S[t][c]);
        float sm = 0.f;
        for (int c = 0; c < 64; ++c) {
            float e = expf(S[t][c] - mx);
            S[t][c] = e;
            sm += e;
        }
        rinv[t] = 1.0f / sm;
    }
    __syncthreads();
    int n = t >> 2, j0 = (t & 3) * 8;
    float inv = rinv[n];
    for (int j = j0; j < j0 + 8; ++j) {
        float s = 0.f;
        for (int c = 0; c < 64; ++c) s += S[n][c] * vh[c][j];
        og[(long)(b * 64 + n) * 256 + hd * 32 + j] = s * inv;
    }
}

// ---------------------------------------------------------------------------
// out = LN(mlp + bilinear_ac(sc, 96->192)) -> NCHW fp32. bf16 inputs.
// ---------------------------------------------------------------------------
__global__ __launch_bounds__(256) void final_k3(
    const u16* __restrict__ mlp, const u16* __restrict__ sc,
    const float* __restrict__ g, const float* __restrict__ bb,
    float* __restrict__ out)
{
    __shared__ float lnb[32][258];
    int blk = blockIdx.x;              // b*1152 + hh*6 + strip
    int b = blk / 1152;
    int rem = blk - b * 1152;
    int hh = rem / 6, ww0 = (rem % 6) * 32;
    int wv = threadIdx.x >> 6, lane = threadIdx.x & 63;
    int c0 = lane * 4;
    float4 g4 = *(const float4*)(g + c0);
    float4 b4 = *(const float4*)(bb + c0);
    float fy = hh * (95.0f / 191.0f);
    int y0 = (int)fy; int y1 = min(y0 + 1, 95); float wy = fy - y0;
    const u16* scb = sc + (long)b * 9216 * 256 + c0;
#pragma unroll
    for (int i = 0; i < 8; ++i) {
        int p = wv * 8 + i;
        int ww = ww0 + p;
        float fx = ww * (95.0f / 191.0f);
        int x0 = (int)fx; int x1 = min(x0 + 1, 95); float wx = fx - x0;
        ushort4 u00 = *(const ushort4*)(scb + (long)(y0 * 96 + x0) * 256);
        ushort4 u01 = *(const ushort4*)(scb + (long)(y0 * 96 + x1) * 256);
        ushort4 u10 = *(const ushort4*)(scb + (long)(y1 * 96 + x0) * 256);
        ushort4 u11 = *(const ushort4*)(scb + (long)(y1 * 96 + x1) * 256);
        long m = ((long)b * 192 + hh) * 192 + ww;
        ushort4 um = *(const ushort4*)(mlp + m * 256 + c0);
        float w00 = (1.f - wy) * (1.f - wx), w01 = (1.f - wy) * wx;
        float w10 = wy * (1.f - wx),         w11 = wy * wx;
        float xv0 = bf2f(um.x) + w00 * bf2f(u00.x) + w01 * bf2f(u01.x) + w10 * bf2f(u10.x) + w11 * bf2f(u11.x);
        float xv1 = bf2f(um.y) + w00 * bf2f(u00.y) + w01 * bf2f(u01.y) + w10 * bf2f(u10.y) + w11 * bf2f(u11.y);
        float xv2 = bf2f(um.z) + w00 * bf2f(u00.z) + w01 * bf2f(u01.z) + w10 * bf2f(u10.z) + w11 * bf2f(u11.z);
        float xv3 = bf2f(um.w) + w00 * bf2f(u00.w) + w01 * bf2f(u01.w) + w10 * bf2f(u10.w) + w11 * bf2f(u11.w);
        float s  = xv0 + xv1 + xv2 + xv3;
        float s2 = xv0 * xv0 + xv1 * xv1 + xv2 * xv2 + xv3 * xv3;
#pragma unroll
        for (int o = 32; o > 0; o >>= 1) {
            s  += __shfl_xor(s,  o, 64);
            s2 += __shfl_xor(s2, o, 64);
        }
        float mean = s * (1.0f / 256.0f);
        float var  = s2 * (1.0f / 256.0f) - mean * mean;
        float rs   = rsqrtf(var + 1e-5f);
        lnb[p][c0 + 0] = (xv0 - mean) * rs * g4.x + b4.x;
        lnb[p][c0 + 1] = (xv1 - mean) * rs * g4.y + b4.y;
        lnb[p][c0 + 2] = (xv2 - mean) * rs * g4.z + b4.z;
        lnb[p][c0 + 3] = (xv3 - mean) * rs * g4.w + b4.w;
    }
    __syncthreads();
    int tw = threadIdx.x & 31, cg = threadIdx.x >> 5;
#pragma unroll
    for (int cc = 0; cc < 32; ++cc) {
        int c = cg * 32 + cc;
        out[((long)(b * 256 + c) * 192 + hh) * 192 + ww0 + tw] = lnb[tw][c];
    }
}

// ---------------------------------------------------------------------------
extern "C" void kernel_launch(void* const* d_in, const int* in_sizes, int n_in,
                              void* d_out, int out_size, void* d_ws, size_t ws_size,
                              hipStream_t stream)
{
    const float* x1     = (const float*)d_in[0];
    const float* x2     = (const float*)d_in[1];
    const float* q_w    = (const float*)d_in[2];
    const float* q_b    = (const float*)d_in[3];
    const float* k_w    = (const float*)d_in[4];
    const float* k_b    = (const float*)d_in[5];
    const float* v_w    = (const float*)d_in[6];
    const float* v_b    = (const float*)d_in[7];
    const float* q2_w   = (const float*)d_in[8];
    const float* q2_b   = (const float*)d_in[9];
    const float* k2_w   = (const float*)d_in[10];
    const float* k2_b   = (const float*)d_in[11];
    const float* v2_w   = (const float*)d_in[12];
    const float* v2_b   = (const float*)d_in[13];
    const float* proj_w = (const float*)d_in[14];
    const float* proj_b = (const float*)d_in[15];
    const float* proj_g = (const float*)d_in[16];
    const float* proj_bt= (const float*)d_in[17];
    const float* n1_g   = (const float*)d_in[18];
    const float* n1_b   = (const float*)d_in[19];
    const float* n2_g   = (const float*)d_in[20];
    const float* n2_b   = (const float*)d_in[21];
    const float* fc1_w  = (const float*)d_in[22];
    const float* fc1_b  = (const float*)d_in[23];
    const float* fc2_w  = (const float*)d_in[24];
    const float* fc2_b  = (const float*)d_in[25];
    float* out = (float*)d_out;

    // workspace carve (bytes), total ~147 MB
    char* p = (char*)d_ws;
    float* scf  = (float*)p;  p += M1 * 256 * 4;        // 18.9 MB proj raw
    u16*   scb  = (u16*)p;    p += M1 * 256 * 2;        //  9.4 MB sc bf16
    float* ktv  = (float*)p;  p += 1024L * 32 * 32 * 4; //  4.2 MB
    u16*   kb16 = (u16*)p;    p += M1 * 256 * 2;        //  9.4 MB
    u16*   vb16 = (u16*)p;    p += M1 * 256 * 2;        //  9.4 MB
    u16*   hln  = (u16*)p;    p += M2 * 256 * 2;        // 37.7 MB
    u16*   h1c  = (u16*)p;    p += 18432L * 512 * 2;    // 18.9 MB
    u16*   mlpb = (u16*)p;    p += M2 * 256 * 2;        // 37.7 MB
    float* qg   = (float*)p;  p += 128L * 256 * 4;
    float* kg   = (float*)p;  p += 128L * 512 * 4;
    float* qg2  = (float*)p;  p += 128L * 256 * 4;
    float* kg2  = (float*)p;  p += 128L * 256 * 4;
    float* vgb  = (float*)p;  p += 128L * 256 * 4;
    float* ogb  = (float*)p;  p += 128L * 256 * 4;

    dim3 blk(256);

    // 0) zero pooled accumulators (qg & kg are contiguous)
    hipMemsetAsync(qg, 0, (128L * 256 + 128L * 512) * 4, stream);

    // 1) proj GEMM -> fp32, then LN -> bf16 sc
    gemm_at<float><<<dim3(2, 144), blk, 0, stream>>>(
        x1, proj_w, proj_b, scf, proj_w, proj_b, scf, 512, 9216, 9216, 512L * 9216);
    ln_sc<<<dim3(18432), blk, 0, stream>>>(scf, scb, proj_g, proj_bt);

    // 2) k & v projections fused (split-N), bf16 out
    gemm_at<u16><<<dim3(4, 144), blk, 0, stream>>>(
        x1, k_w, k_b, kb16, v_w, v_b, vb16, 512, 9216, 9216, 512L * 9216);

    // 3) per (window, head) K^T V
    ktv_kernel<<<dim3(1024), blk, 0, stream>>>(kb16, vb16, ktv);

    // 4) pooled q/k (+pos after)
    pool_q2<<<dim3(3072), blk, 0, stream>>>(x2, qg);
    pool_k2<<<dim3(1536), blk, 0, stream>>>(x1, kg);
    posfix<<<dim3(128), blk, 0, stream>>>(qg, kg);

    // 5-7) global projections (tiny, fp32)
    gemm64<0><<<dim3(4, 2), blk, 0, stream>>>(qg, q2_w, q2_b, qg2, 256, 256, 256);
    gemm64<0><<<dim3(4, 2), blk, 0, stream>>>(kg, k2_w, k2_b, kg2, 256, 512, 512);
    gemm64<0><<<dim3(4, 2), blk, 0, stream>>>(kg, v2_w, v2_b, vgb, 256, 512, 512);

    // 8) global softmax attention
    gattn<<<dim3(16), blk, 0, stream>>>(qg2, kg2, vgb, ogb);

    // 9) fully fused q-proj + window attn + residual + og upsample + LN1
    wattn_ln<<<dim3(1536), blk, 0, stream>>>(x2, q_w, q_b, ktv, ogb, hln, n1_g, n1_b);

    // 10-11) MLP, chunked x4 over rows; all-bf16 A operands
    for (int c4 = 0; c4 < 4; ++c4) {
        const u16* aoff = hln  + (long)c4 * 18432 * 256;
        u16*       coff = mlpb + (long)c4 * 18432 * 256;
        gemm_bf16rm<1><<<dim3(4, 144), blk, 0, stream>>>(
            aoff, fc1_w, fc1_b, h1c, 512, 256, 256);
        gemm_bf16rm<0><<<dim3(2, 144), blk, 0, stream>>>(
            h1c, fc2_w, fc2_b, coff, 256, 512, 512);
    }

    // 12) out = LN(mlp + upsample(sc)) -> NCHW
    final_k3<<<dim3(2304), blk, 0, stream>>>(mlpb, scb, n2_g, n2_b, out);
}